// Round 5
// baseline (280.686 us; speedup 1.0000x reference)
//
#include <hip/hip_runtime.h>
#include <hip/hip_bf16.h>
#include <stdint.h>

typedef __attribute__((ext_vector_type(8))) short short8;
typedef __attribute__((ext_vector_type(4))) short s16x4;
typedef __attribute__((ext_vector_type(4))) float floatx4;
typedef __attribute__((ext_vector_type(4))) unsigned short ushortx4;

#define T_LEN 2048
#define C_DIM 1024
#define NH 16
#define HD 64

static __device__ __forceinline__ unsigned short f2bf(float f) {
  union { float f; unsigned u; } v; v.f = f;
  unsigned r = v.u + 0x7fffu + ((v.u >> 16) & 1u);
  return (unsigned short)(r >> 16);
}

static __device__ __forceinline__ void stage16(const void* g, void* l) {
  __builtin_amdgcn_global_load_lds(
      (const __attribute__((address_space(1))) void*)g,
      (__attribute__((address_space(3))) void*)l, 16, 0, 0);
}

// 16x16x16 bf16 MFMA via inline asm (A,B = 2 VGPRs each, C/D = 4; D==C in place)
static __device__ __forceinline__ floatx4 mfma16(s16x4 a, s16x4 b, floatx4 c) {
  asm("v_mfma_f32_16x16x16_bf16 %0, %1, %2, %0" : "+v"(c) : "v"(a), "v"(b));
  return c;
}
// pack 2 f32 -> 1 dword of 2 bf16 (lo = s0, hi = s1)
static __device__ __forceinline__ unsigned cvt_pk_bf16(float lo, float hi) {
  unsigned r;
  asm("v_cvt_pk_bf16_f32 %0, %1, %2" : "=v"(r) : "v"(lo), "v"(hi));
  return r;
}

// ---------------- cast x (f32 -> bf16), 4 elems/thread ----------------
__global__ __launch_bounds__(256) void cast_x(const float* __restrict__ in,
                                              unsigned short* __restrict__ out) {
  const long i = (long)(blockIdx.x * 256 + threadIdx.x) * 4;
  const float4 v = *(const float4*)(in + i);
  ushortx4 o;
  o[0] = f2bf(v.x); o[1] = f2bf(v.y); o[2] = f2bf(v.z); o[3] = f2bf(v.w);
  *(ushortx4*)(out + i) = o;
}

// ---------- transpose + cast: in [R][C] f32 -> out [C][R] bf16 ----------
__global__ __launch_bounds__(256) void transpose_cast(
    const float* __restrict__ in, unsigned short* __restrict__ out, int R, int C) {
  __shared__ unsigned short tile[64][72];
  const int r0 = blockIdx.y * 64;
  const int c0 = blockIdx.x * 64;
  const int tid = threadIdx.x;
#pragma unroll
  for (int e = 0; e < 4; ++e) {
    const int ch = e * 256 + tid;           // 1024 chunks of 4 floats
    const int r = ch >> 4, c4 = (ch & 15) * 4;
    const float4 v = *(const float4*)(in + (long)(r0 + r) * C + c0 + c4);
    tile[r][c4 + 0] = f2bf(v.x);
    tile[r][c4 + 1] = f2bf(v.y);
    tile[r][c4 + 2] = f2bf(v.z);
    tile[r][c4 + 3] = f2bf(v.w);
  }
  __syncthreads();
#pragma unroll
  for (int e = 0; e < 2; ++e) {
    const int ch = e * 256 + tid;           // 512 chunks of 8
    const int c = ch >> 3, k8 = (ch & 7) * 8;
    short8 w;
#pragma unroll
    for (int j = 0; j < 8; ++j) w[j] = (short)tile[k8 + j][c];
    *(short8*)(out + (long)(c0 + c) * R + r0 + k8) = w;
  }
}

// ---- V transpose (bf16): [bh][T][D] -> [bh][D][T], 64x64 tiles ----
__global__ __launch_bounds__(256) void vtrans(
    const unsigned short* __restrict__ in, unsigned short* __restrict__ out) {
  __shared__ unsigned short tile[64][72];
  const int bh = blockIdx.y;
  const int t0 = blockIdx.x * 64;
  const int tid = threadIdx.x;
  const unsigned short* src = in + (long)bh * T_LEN * HD + (long)t0 * HD;
#pragma unroll
  for (int e = 0; e < 2; ++e) {
    const int ch = e * 256 + tid;
    const int r = ch >> 3, c8 = (ch & 7) * 8;
    *(short8*)&tile[r][c8] = *(const short8*)(src + r * HD + c8);
  }
  __syncthreads();
  unsigned short* dst = out + (long)bh * HD * T_LEN + t0;
#pragma unroll
  for (int e = 0; e < 2; ++e) {
    const int ch = e * 256 + tid;
    const int d = ch >> 3, t8 = (ch & 7) * 8;
    short8 w;
#pragma unroll
    for (int j = 0; j < 8; ++j) w[j] = (short)tile[t8 + j][d];
    *(short8*)(dst + (long)d * T_LEN + t8) = w;
  }
}

// ---------------- GEMM: C = A[M,K] * Bt[N,K]^T + bias ----------------
// 128x128 tile, BK=32, 256 threads (4 waves, 2x2 of 64x64 subtiles).
// MODE 0: scatter to Q/K/V head layouts (Q scaled by 0.125*log2e), bf16 out.
// MODE 1: fp32 out row-major [M][N].
template <int MODE>
__global__ __launch_bounds__(256) void gemm_bt(
    const unsigned short* __restrict__ A,
    const unsigned short* __restrict__ Bt,
    const float* __restrict__ bias,
    int M, int N, int K,
    unsigned short* __restrict__ q_out,
    unsigned short* __restrict__ k_out,
    unsigned short* __restrict__ v_out,
    float* __restrict__ f_out) {
  __shared__ unsigned short As[128 * 32];
  __shared__ unsigned short Bs[128 * 32];
  const int tid = threadIdx.x;
  const int lane = tid & 63;
  const int wid = tid >> 6;
  const int wr = wid >> 1, wc = wid & 1;
  const int lrow = lane & 15, lgrp = lane >> 4;
  const long row0 = (long)blockIdx.y * 128;
  const long col0 = (long)blockIdx.x * 128;

  floatx4 acc[4][4];
#pragma unroll
  for (int m = 0; m < 4; ++m)
#pragma unroll
    for (int n = 0; n < 4; ++n)
      acc[m][n] = (floatx4){0.f, 0.f, 0.f, 0.f};

  const unsigned short* Abase = A + row0 * K;
  const unsigned short* Bbase = Bt + col0 * K;

  for (int k0 = 0; k0 < K; k0 += 32) {
#pragma unroll
    for (int r = 0; r < 2; ++r) {
      const int ch = r * 256 + tid;        // 16B chunk id in [0,512)
      const int trow = ch >> 2, tcol = (ch & 3) * 8;
      stage16(Abase + (long)trow * K + k0 + tcol, &As[(r * 256 + wid * 64) * 8]);
      stage16(Bbase + (long)trow * K + k0 + tcol, &Bs[(r * 256 + wid * 64) * 8]);
    }
    __syncthreads();
    short8 af[4], bf[4];
#pragma unroll
    for (int m = 0; m < 4; ++m)
      af[m] = *(const short8*)&As[(wr * 64 + m * 16 + lrow) * 32 + lgrp * 8];
#pragma unroll
    for (int n = 0; n < 4; ++n)
      bf[n] = *(const short8*)&Bs[(wc * 64 + n * 16 + lrow) * 32 + lgrp * 8];
#pragma unroll
    for (int m = 0; m < 4; ++m)
#pragma unroll
      for (int n = 0; n < 4; ++n)
        acc[m][n] = __builtin_amdgcn_mfma_f32_16x16x32_bf16(af[m], bf[n], acc[m][n], 0, 0, 0);
    __syncthreads();
  }

  if (MODE == 0) {
#pragma unroll
    for (int n = 0; n < 4; ++n) {
      const int c = (int)col0 + wc * 64 + n * 16 + lrow;
      const float bs = bias[c];
      const int sect = c >> 10;            // 0=Q 1=K 2=V
      const int h = (c & 1023) >> 6;
      const int d = c & 63;
      unsigned short* dst = sect == 0 ? q_out : (sect == 1 ? k_out : v_out);
      // fold 1/sqrt(64) AND log2(e) into Q (attn uses exp2)
      const float scl = sect == 0 ? 0.18033688011112042f : 1.0f;
#pragma unroll
      for (int m = 0; m < 4; ++m) {
#pragma unroll
        for (int i = 0; i < 4; ++i) {
          const long r = row0 + wr * 64 + m * 16 + lgrp * 4 + i;
          const long b = r >> 11;          // r / 2048
          const long t = r & 2047;
          const float val = (acc[m][n][i] + bs) * scl;
          dst[((b * NH + h) * T_LEN + t) * HD + d] = f2bf(val);
        }
      }
    }
  } else {
#pragma unroll
    for (int n = 0; n < 4; ++n) {
      const int c = (int)col0 + wc * 64 + n * 16 + lrow;
      const float bs = bias[c];
#pragma unroll
      for (int m = 0; m < 4; ++m) {
#pragma unroll
        for (int i = 0; i < 4; ++i) {
          const long r = row0 + wr * 64 + m * 16 + lgrp * 4 + i;
          f_out[r * (long)N + c] = acc[m][n][i] + bs;
        }
      }
    }
  }
}

// ------- flash attention v5: KV-split 4 waves + K reg-double-buffer + exp2 -------
// Block = (bh, qt): 32 q-rows, waves split KV steps (wave w: steps w, w+4, ...).
// Swapped QK^T -> lane-local softmax; reg-direct PV (16x16x16); K prefetched
// one step ahead into alternate register set (static dbuf, 2x-unrolled loop).
// Grid 1-D XCD-clustered (4 heads/XCD => KV in XCD L2), qt reversed (long first).
// One step: V loads -> next-K prefetch -> QK^T(cur K) -> mask -> softmax -> PV.
#define ATTN_STEP(KCUR, KNXT, ST) do {                                                          \
    const int s0 = (ST) * 64;                                                                   \
    s16x4 vb[4][4];                                                                             \
    _Pragma("unroll") for (int d0 = 0; d0 < 4; ++d0)                                            \
      _Pragma("unroll") for (int sc = 0; sc < 4; ++sc)                                          \
        vb[d0][sc] = *(const s16x4*)(Vh + (long)(d0 * 16 + lrow) * T_LEN + s0 + sc * 16 + lgrp * 4); \
    _Pragma("unroll") for (int sc = 0; sc < 4; ++sc)                                            \
      _Pragma("unroll") for (int kk = 0; kk < 2; ++kk)                                          \
        KNXT[sc][kk] = *(const short8*)(Kh + (long)(s0 + 256 + sc * 16 + lrow) * HD + kk * 32 + lgrp * 8); \
    floatx4 sf[2][4];                                                                           \
    _Pragma("unroll") for (int qs = 0; qs < 2; ++qs)                                            \
      _Pragma("unroll") for (int sc = 0; sc < 4; ++sc)                                          \
        sf[qs][sc] = (floatx4){0.f, 0.f, 0.f, 0.f};                                             \
    _Pragma("unroll") for (int sc = 0; sc < 4; ++sc)                                            \
      _Pragma("unroll") for (int kk = 0; kk < 2; ++kk) {                                        \
        sf[0][sc] = __builtin_amdgcn_mfma_f32_16x16x32_bf16(KCUR[sc][kk], aq[0][kk], sf[0][sc], 0, 0, 0); \
        sf[1][sc] = __builtin_amdgcn_mfma_f32_16x16x32_bf16(KCUR[sc][kk], aq[1][kk], sf[1][sc], 0, 0, 0); \
      }                                                                                         \
    if (s0 + 64 > q0) {                                                                         \
      _Pragma("unroll") for (int qs = 0; qs < 2; ++qs) {                                        \
        const int q = q0 + qs * 16 + lrow;                                                      \
        _Pragma("unroll") for (int sc = 0; sc < 4; ++sc)                                        \
          _Pragma("unroll") for (int i = 0; i < 4; ++i) {                                       \
            const int s = s0 + sc * 16 + lgrp * 4 + i;                                          \
            if (s > q) sf[qs][sc][i] = -1e30f;                                                  \
          }                                                                                     \
      }                                                                                         \
    }                                                                                           \
    s16x4 pa[2][4];                                                                             \
    _Pragma("unroll") for (int qs = 0; qs < 2; ++qs) {                                          \
      float m0 = fmaxf(fmaxf(sf[qs][0][0], sf[qs][0][1]), fmaxf(sf[qs][0][2], sf[qs][0][3]));   \
      float m1 = fmaxf(fmaxf(sf[qs][1][0], sf[qs][1][1]), fmaxf(sf[qs][1][2], sf[qs][1][3]));   \
      float m2 = fmaxf(fmaxf(sf[qs][2][0], sf[qs][2][1]), fmaxf(sf[qs][2][2], sf[qs][2][3]));   \
      float m3 = fmaxf(fmaxf(sf[qs][3][0], sf[qs][3][1]), fmaxf(sf[qs][3][2], sf[qs][3][3]));   \
      float mm = fmaxf(fmaxf(m0, m1), fmaxf(m2, m3));                                           \
      mm = fmaxf(mm, __shfl_xor(mm, 16));                                                       \
      mm = fmaxf(mm, __shfl_xor(mm, 32));                                                       \
      const float mnew = fmaxf(m_i[qs], mm);                                                    \
      const float scale = exp2f(m_i[qs] - mnew);                                                \
      float rs = 0.f;                                                                           \
      _Pragma("unroll") for (int sc = 0; sc < 4; ++sc)                                          \
        _Pragma("unroll") for (int i = 0; i < 4; ++i) {                                         \
          const float pv = exp2f(sf[qs][sc][i] - mnew);                                         \
          sf[qs][sc][i] = pv;                                                                   \
          rs += pv;                                                                             \
        }                                                                                       \
      rs += __shfl_xor(rs, 16);                                                                 \
      rs += __shfl_xor(rs, 32);                                                                 \
      m_i[qs] = mnew;                                                                           \
      s_i[qs] = s_i[qs] * scale + rs;                                                           \
      _Pragma("unroll") for (int i = 0; i < 4; ++i) {                                           \
        const float sbc = __shfl(scale, 4 * lgrp + i);                                          \
        _Pragma("unroll") for (int d0 = 0; d0 < 4; ++d0) o[qs][d0][i] *= sbc;                   \
      }                                                                                         \
      _Pragma("unroll") for (int sc = 0; sc < 4; ++sc) {                                        \
        union { unsigned u[2]; s16x4 v; } tmp;                                                  \
        tmp.u[0] = cvt_pk_bf16(sf[qs][sc][0], sf[qs][sc][1]);                                   \
        tmp.u[1] = cvt_pk_bf16(sf[qs][sc][2], sf[qs][sc][3]);                                   \
        pa[qs][sc] = tmp.v;                                                                     \
      }                                                                                         \
    }                                                                                           \
    _Pragma("unroll") for (int d0 = 0; d0 < 4; ++d0)                                            \
      _Pragma("unroll") for (int sc = 0; sc < 4; ++sc) {                                        \
        o[0][d0] = mfma16(pa[0][sc], vb[d0][sc], o[0][d0]);                                     \
        o[1][d0] = mfma16(pa[1][sc], vb[d0][sc], o[1][d0]);                                     \
      }                                                                                         \
  } while (0)

__global__ __launch_bounds__(256) void attn_fwd(
    const unsigned short* __restrict__ Qb,
    const unsigned short* __restrict__ Kb,
    const unsigned short* __restrict__ Vt,
    unsigned short* __restrict__ attn) {
  __shared__ float o_lds[4][32][68];      // [wave][q][d] padded stride 68
  __shared__ float mshare[4][2][16];
  __shared__ float sshare[4][2][16];
  const int bid = (int)blockIdx.x;
  const int xcd = bid & 7;
  const int j = bid >> 3;
  const int bh = xcd * 4 + (j & 3);       // 4 heads per XCD -> KV in XCD L2
  const int qt = 63 - (j >> 2);           // reversed: long blocks first
  const int b = bh >> 4, h = bh & 15;
  const int wid = (int)threadIdx.x >> 6;
  const int lane = (int)threadIdx.x & 63;
  const int lrow = lane & 15, lgrp = lane >> 4;
  const int q0 = qt * 32;
  const int nsteps = (q0 + 32 + 63) >> 6; // ceil((q0+32)/64)

  const unsigned short* Qh = Qb + (long)bh * T_LEN * HD;
  const unsigned short* Kh = Kb + (long)bh * T_LEN * HD;
  const unsigned short* Vh = Vt + (long)bh * HD * T_LEN;

  // Q fragments (B operand of swapped QK^T): [qsub][kk]
  short8 aq[2][2];
#pragma unroll
  for (int qs = 0; qs < 2; ++qs)
#pragma unroll
    for (int kk = 0; kk < 2; ++kk)
      aq[qs][kk] = *(const short8*)(Qh + (long)(q0 + qs * 16 + lrow) * HD + kk * 32 + lgrp * 8);

  float m_i[2] = {-1e30f, -1e30f};
  float s_i[2] = {0.f, 0.f};
  floatx4 o[2][4];                        // O[q=16qs+4lg+i][d=16d0+lrow]
#pragma unroll
  for (int qs = 0; qs < 2; ++qs)
#pragma unroll
    for (int d0 = 0; d0 < 4; ++d0) o[qs][d0] = (floatx4){0.f, 0.f, 0.f, 0.f};

  // software-pipelined KV loop: K double-buffered in registers (static names)
  short8 kfA[4][2], kfB[4][2];
  int st = wid;
  if (st < nsteps) {
#pragma unroll
    for (int sc = 0; sc < 4; ++sc)
#pragma unroll
      for (int kk = 0; kk < 2; ++kk)
        kfA[sc][kk] = *(const short8*)(Kh + (long)(st * 64 + sc * 16 + lrow) * HD + kk * 32 + lgrp * 8);
    while (true) {
      ATTN_STEP(kfA, kfB, st);
      st += 4; if (st >= nsteps) break;
      ATTN_STEP(kfB, kfA, st);
      st += 4; if (st >= nsteps) break;
    }
  }

  // ---- combine the 4 per-wave partials ----
  mshare[wid][0][lrow] = m_i[0];          // uniform across lgrp (same value, same addr)
  mshare[wid][1][lrow] = m_i[1];
  __syncthreads();
#pragma unroll
  for (int qs = 0; qs < 2; ++qs) {
    const float gm = fmaxf(fmaxf(mshare[0][qs][lrow], mshare[1][qs][lrow]),
                           fmaxf(mshare[2][qs][lrow], mshare[3][qs][lrow]));
    const float f = exp2f(m_i[qs] - gm);
    sshare[wid][qs][lrow] = s_i[qs] * f;
#pragma unroll
    for (int i = 0; i < 4; ++i) {
      const float fb = __shfl(f, 4 * lgrp + i);
#pragma unroll
      for (int d0 = 0; d0 < 4; ++d0)
        o_lds[wid][qs * 16 + lgrp * 4 + i][d0 * 16 + lrow] = o[qs][d0][i] * fb;
    }
  }
  __syncthreads();
  // ---- final reduce + write: thread t -> q = t>>3, 8 d-values ----
  const int t = (int)threadIdx.x;
  const int q = t >> 3;
  const int d8 = (t & 7) * 8;
  const int qss = q >> 4, qr = q & 15;
  const float S = sshare[0][qss][qr] + sshare[1][qss][qr] +
                  sshare[2][qss][qr] + sshare[3][qss][qr];
  const float invS = 1.0f / S;
  short8 wv;
#pragma unroll
  for (int jj = 0; jj < 8; ++jj) {
    const float acc = o_lds[0][q][d8 + jj] + o_lds[1][q][d8 + jj] +
                      o_lds[2][q][d8 + jj] + o_lds[3][q][d8 + jj];
    wv[jj] = (short)f2bf(acc * invS);
  }
  *(short8*)(attn + (long)(b * T_LEN + q0 + q) * C_DIM + h * HD + d8) = wv;
}

extern "C" void kernel_launch(void* const* d_in, const int* in_sizes, int n_in,
                              void* d_out, int out_size, void* d_ws, size_t ws_size,
                              hipStream_t stream) {
  const float* x     = (const float*)d_in[0];
  const float* Wqkv  = (const float*)d_in[1];
  const float* bqkv  = (const float*)d_in[2];
  const float* Wproj = (const float*)d_in[3];
  const float* bproj = (const float*)d_in[4];
  float* out = (float*)d_out;
  char* ws = (char*)d_ws;
  const size_t MB = 1024 * 1024;
  unsigned short* Qb     = (unsigned short*)(ws + 0 * MB);   // [B,N,T,D] bf16, scaled log2e/8
  unsigned short* Kb     = (unsigned short*)(ws + 8 * MB);   // [B,N,T,D]
  unsigned short* Vb     = (unsigned short*)(ws + 16 * MB);  // [B,N,T,D]
  unsigned short* Vt     = (unsigned short*)(ws + 24 * MB);  // [B,N,D,T]
  unsigned short* attn   = (unsigned short*)(ws + 32 * MB);  // [B,T,C]
  unsigned short* xbf    = (unsigned short*)(ws + 40 * MB);  // [B*T,C]
  unsigned short* Wqkvt  = (unsigned short*)(ws + 48 * MB);  // [3C,C]
  unsigned short* Wprojt = (unsigned short*)(ws + 54 * MB);  // [C,C]

  cast_x<<<4096, 256, 0, stream>>>(x, xbf);
  transpose_cast<<<dim3(48, 16), 256, 0, stream>>>(Wqkv, Wqkvt, 1024, 3072);
  transpose_cast<<<dim3(16, 16), 256, 0, stream>>>(Wproj, Wprojt, 1024, 1024);
  gemm_bt<0><<<dim3(24, 32), 256, 0, stream>>>(xbf, Wqkvt, bqkv, 4096, 3072, 1024,
                                               Qb, Kb, Vb, nullptr);
  vtrans<<<dim3(32, 32), 256, 0, stream>>>(Vb, Vt);
  attn_fwd<<<2048, 256, 0, stream>>>(Qb, Kb, Vt, attn);
  gemm_bt<1><<<dim3(8, 32), 256, 0, stream>>>(attn, Wprojt, bproj, 4096, 1024, 1024,
                                              nullptr, nullptr, nullptr, out);
}

// Round 6
// 269.214 us; speedup vs baseline: 1.0426x; 1.0426x over previous
//
#include <hip/hip_runtime.h>
#include <hip/hip_bf16.h>
#include <stdint.h>

typedef __attribute__((ext_vector_type(8))) short short8;
typedef __attribute__((ext_vector_type(4))) short s16x4;
typedef __attribute__((ext_vector_type(4))) float floatx4;
typedef __attribute__((ext_vector_type(4))) unsigned short ushortx4;

#define T_LEN 2048
#define C_DIM 1024
#define NH 16
#define HD 64

static __device__ __forceinline__ unsigned short f2bf(float f) {
  union { float f; unsigned u; } v; v.f = f;
  unsigned r = v.u + 0x7fffu + ((v.u >> 16) & 1u);
  return (unsigned short)(r >> 16);
}

static __device__ __forceinline__ void stage16(const void* g, void* l) {
  __builtin_amdgcn_global_load_lds(
      (const __attribute__((address_space(1))) void*)g,
      (__attribute__((address_space(3))) void*)l, 16, 0, 0);
}

// 16x16x16 bf16 MFMA via inline asm (A,B = 2 VGPRs each, C/D = 4; D==C in place)
static __device__ __forceinline__ floatx4 mfma16(s16x4 a, s16x4 b, floatx4 c) {
  asm("v_mfma_f32_16x16x16_bf16 %0, %1, %2, %0" : "+v"(c) : "v"(a), "v"(b));
  return c;
}
// pack 2 f32 -> 1 dword of 2 bf16 (lo = s0, hi = s1)
static __device__ __forceinline__ unsigned cvt_pk_bf16(float lo, float hi) {
  unsigned r;
  asm("v_cvt_pk_bf16_f32 %0, %1, %2" : "=v"(r) : "v"(lo), "v"(hi));
  return r;
}

// ---------------- cast x (f32 -> bf16), 4 elems/thread ----------------
__global__ __launch_bounds__(256) void cast_x(const float* __restrict__ in,
                                              unsigned short* __restrict__ out) {
  const long i = (long)(blockIdx.x * 256 + threadIdx.x) * 4;
  const float4 v = *(const float4*)(in + i);
  ushortx4 o;
  o[0] = f2bf(v.x); o[1] = f2bf(v.y); o[2] = f2bf(v.z); o[3] = f2bf(v.w);
  *(ushortx4*)(out + i) = o;
}

// ---------- transpose + cast: in [R][C] f32 -> out [C][R] bf16 ----------
__global__ __launch_bounds__(256) void transpose_cast(
    const float* __restrict__ in, unsigned short* __restrict__ out, int R, int C) {
  __shared__ unsigned short tile[64][72];
  const int r0 = blockIdx.y * 64;
  const int c0 = blockIdx.x * 64;
  const int tid = threadIdx.x;
#pragma unroll
  for (int e = 0; e < 4; ++e) {
    const int ch = e * 256 + tid;           // 1024 chunks of 4 floats
    const int r = ch >> 4, c4 = (ch & 15) * 4;
    const float4 v = *(const float4*)(in + (long)(r0 + r) * C + c0 + c4);
    tile[r][c4 + 0] = f2bf(v.x);
    tile[r][c4 + 1] = f2bf(v.y);
    tile[r][c4 + 2] = f2bf(v.z);
    tile[r][c4 + 3] = f2bf(v.w);
  }
  __syncthreads();
#pragma unroll
  for (int e = 0; e < 2; ++e) {
    const int ch = e * 256 + tid;           // 512 chunks of 8
    const int c = ch >> 3, k8 = (ch & 7) * 8;
    short8 w;
#pragma unroll
    for (int j = 0; j < 8; ++j) w[j] = (short)tile[k8 + j][c];
    *(short8*)(out + (long)(c0 + c) * R + r0 + k8) = w;
  }
}

// ---- V transpose (bf16): [bh][T][D] -> [bh][D][T], 64x64 tiles ----
__global__ __launch_bounds__(256) void vtrans(
    const unsigned short* __restrict__ in, unsigned short* __restrict__ out) {
  __shared__ unsigned short tile[64][72];
  const int bh = blockIdx.y;
  const int t0 = blockIdx.x * 64;
  const int tid = threadIdx.x;
  const unsigned short* src = in + (long)bh * T_LEN * HD + (long)t0 * HD;
#pragma unroll
  for (int e = 0; e < 2; ++e) {
    const int ch = e * 256 + tid;
    const int r = ch >> 3, c8 = (ch & 7) * 8;
    *(short8*)&tile[r][c8] = *(const short8*)(src + r * HD + c8);
  }
  __syncthreads();
  unsigned short* dst = out + (long)bh * HD * T_LEN + t0;
#pragma unroll
  for (int e = 0; e < 2; ++e) {
    const int ch = e * 256 + tid;
    const int d = ch >> 3, t8 = (ch & 7) * 8;
    short8 w;
#pragma unroll
    for (int j = 0; j < 8; ++j) w[j] = (short)tile[t8 + j][d];
    *(short8*)(dst + (long)d * T_LEN + t8) = w;
  }
}

// ---------------- GEMM: C = A[M,K] * Bt[N,K]^T + bias ----------------
// 128x128 tile, BK=32, 256 threads (4 waves, 2x2 of 64x64 subtiles).
// MODE 0: scatter to Q/K/V head layouts (Q scaled by 0.125*log2e), bf16 out.
// MODE 1: fp32 out row-major [M][N].
template <int MODE>
__global__ __launch_bounds__(256) void gemm_bt(
    const unsigned short* __restrict__ A,
    const unsigned short* __restrict__ Bt,
    const float* __restrict__ bias,
    int M, int N, int K,
    unsigned short* __restrict__ q_out,
    unsigned short* __restrict__ k_out,
    unsigned short* __restrict__ v_out,
    float* __restrict__ f_out) {
  __shared__ unsigned short As[128 * 32];
  __shared__ unsigned short Bs[128 * 32];
  const int tid = threadIdx.x;
  const int lane = tid & 63;
  const int wid = tid >> 6;
  const int wr = wid >> 1, wc = wid & 1;
  const int lrow = lane & 15, lgrp = lane >> 4;
  const long row0 = (long)blockIdx.y * 128;
  const long col0 = (long)blockIdx.x * 128;

  floatx4 acc[4][4];
#pragma unroll
  for (int m = 0; m < 4; ++m)
#pragma unroll
    for (int n = 0; n < 4; ++n)
      acc[m][n] = (floatx4){0.f, 0.f, 0.f, 0.f};

  const unsigned short* Abase = A + row0 * K;
  const unsigned short* Bbase = Bt + col0 * K;

  for (int k0 = 0; k0 < K; k0 += 32) {
#pragma unroll
    for (int r = 0; r < 2; ++r) {
      const int ch = r * 256 + tid;        // 16B chunk id in [0,512)
      const int trow = ch >> 2, tcol = (ch & 3) * 8;
      stage16(Abase + (long)trow * K + k0 + tcol, &As[(r * 256 + wid * 64) * 8]);
      stage16(Bbase + (long)trow * K + k0 + tcol, &Bs[(r * 256 + wid * 64) * 8]);
    }
    __syncthreads();
    short8 af[4], bf[4];
#pragma unroll
    for (int m = 0; m < 4; ++m)
      af[m] = *(const short8*)&As[(wr * 64 + m * 16 + lrow) * 32 + lgrp * 8];
#pragma unroll
    for (int n = 0; n < 4; ++n)
      bf[n] = *(const short8*)&Bs[(wc * 64 + n * 16 + lrow) * 32 + lgrp * 8];
#pragma unroll
    for (int m = 0; m < 4; ++m)
#pragma unroll
      for (int n = 0; n < 4; ++n)
        acc[m][n] = __builtin_amdgcn_mfma_f32_16x16x32_bf16(af[m], bf[n], acc[m][n], 0, 0, 0);
    __syncthreads();
  }

  if (MODE == 0) {
#pragma unroll
    for (int n = 0; n < 4; ++n) {
      const int c = (int)col0 + wc * 64 + n * 16 + lrow;
      const float bs = bias[c];
      const int sect = c >> 10;            // 0=Q 1=K 2=V
      const int h = (c & 1023) >> 6;
      const int d = c & 63;
      unsigned short* dst = sect == 0 ? q_out : (sect == 1 ? k_out : v_out);
      // fold 1/sqrt(64) AND log2(e) into Q (attn uses exp2)
      const float scl = sect == 0 ? 0.18033688011112042f : 1.0f;
#pragma unroll
      for (int m = 0; m < 4; ++m) {
#pragma unroll
        for (int i = 0; i < 4; ++i) {
          const long r = row0 + wr * 64 + m * 16 + lgrp * 4 + i;
          const long b = r >> 11;          // r / 2048
          const long t = r & 2047;
          const float val = (acc[m][n][i] + bs) * scl;
          dst[((b * NH + h) * T_LEN + t) * HD + d] = f2bf(val);
        }
      }
    }
  } else {
#pragma unroll
    for (int n = 0; n < 4; ++n) {
      const int c = (int)col0 + wc * 64 + n * 16 + lrow;
      const float bs = bias[c];
#pragma unroll
      for (int m = 0; m < 4; ++m) {
#pragma unroll
        for (int i = 0; i < 4; ++i) {
          const long r = row0 + wr * 64 + m * 16 + lgrp * 4 + i;
          f_out[r * (long)N + c] = acc[m][n][i] + bs;
        }
      }
    }
  }
}

// ------- flash attention v6: equal-work paired q-tiles, KV-split 4 waves -------
// Block handles TWO q-tiles (qtA = 63-p long, qtB = p short) => every block does
// ~33 KV-steps: 1024 equal-work blocks = one generation on 1024 co-resident slots.
// Per tile: 32 q rows, waves split KV steps (wave w: steps w, w+4, ...).
// Swapped QK^T -> lane-local softmax (exp2); reg-direct PV (16x16x16 MFMA).
// Grid 1-D XCD-clustered (4 heads/XCD => KV stays in XCD L2).
__device__ __forceinline__ void attn_tile(
    const unsigned short* __restrict__ Qh,
    const unsigned short* __restrict__ Kh,
    const unsigned short* __restrict__ Vh,
    unsigned short* __restrict__ outp,    // attn + b*T*C + h*HD
    int q0, int wid, int lane, int lrow, int lgrp,
    float (*o_lds)[32][68], float (*mshare)[2][16], float (*sshare)[2][16]) {
  const int nsteps = (q0 + 32 + 63) >> 6;     // ceil((q0+32)/64)

  // Q fragments (B operand of swapped QK^T): [qsub][kk]
  short8 aq[2][2];
#pragma unroll
  for (int qs = 0; qs < 2; ++qs)
#pragma unroll
    for (int kk = 0; kk < 2; ++kk)
      aq[qs][kk] = *(const short8*)(Qh + (long)(q0 + qs * 16 + lrow) * HD + kk * 32 + lgrp * 8);

  float m_i[2] = {-1e30f, -1e30f};
  float s_i[2] = {0.f, 0.f};
  floatx4 o[2][4];                            // O[q=16qs+4lg+i][d=16d0+lrow]
#pragma unroll
  for (int qs = 0; qs < 2; ++qs)
#pragma unroll
    for (int d0 = 0; d0 < 4; ++d0) o[qs][d0] = (floatx4){0.f, 0.f, 0.f, 0.f};

  for (int st = wid; st < nsteps; st += 4) {
    const int s0 = st * 64;
    // hoisted K loads (8x16B) and V loads (16x8B): pipeline together
    short8 kf[4][2];
#pragma unroll
    for (int sc = 0; sc < 4; ++sc)
#pragma unroll
      for (int kk = 0; kk < 2; ++kk)
        kf[sc][kk] = *(const short8*)(Kh + (long)(s0 + sc * 16 + lrow) * HD + kk * 32 + lgrp * 8);
    s16x4 vb[4][4];                           // [d0][sc]
#pragma unroll
    for (int d0 = 0; d0 < 4; ++d0)
#pragma unroll
      for (int sc = 0; sc < 4; ++sc)
        vb[d0][sc] = *(const s16x4*)(Vh + (long)(d0 * 16 + lrow) * T_LEN + s0 + sc * 16 + lgrp * 4);
    // QK^T (swapped): sf[qs][sc][i] = S[q=q0+16qs+lrow][s=s0+16sc+4lg+i]
    floatx4 sf[2][4];
#pragma unroll
    for (int qs = 0; qs < 2; ++qs)
#pragma unroll
      for (int sc = 0; sc < 4; ++sc) sf[qs][sc] = (floatx4){0.f, 0.f, 0.f, 0.f};
#pragma unroll
    for (int sc = 0; sc < 4; ++sc) {
#pragma unroll
      for (int kk = 0; kk < 2; ++kk) {
        sf[0][sc] = __builtin_amdgcn_mfma_f32_16x16x32_bf16(kf[sc][kk], aq[0][kk], sf[0][sc], 0, 0, 0);
        sf[1][sc] = __builtin_amdgcn_mfma_f32_16x16x32_bf16(kf[sc][kk], aq[1][kk], sf[1][sc], 0, 0, 0);
      }
    }
    // causal mask (diagonal step only)
    if (s0 + 64 > q0) {
#pragma unroll
      for (int qs = 0; qs < 2; ++qs) {
        const int q = q0 + qs * 16 + lrow;
#pragma unroll
        for (int sc = 0; sc < 4; ++sc) {
#pragma unroll
          for (int i = 0; i < 4; ++i) {
            const int s = s0 + sc * 16 + lgrp * 4 + i;
            if (s > q) sf[qs][sc][i] = -1e30f;
          }
        }
      }
    }
    // online softmax: row lane-local (16 vals) + 2 shfl_xor; exp2 domain
    s16x4 pa[2][4];
#pragma unroll
    for (int qs = 0; qs < 2; ++qs) {
      float m0 = fmaxf(fmaxf(sf[qs][0][0], sf[qs][0][1]), fmaxf(sf[qs][0][2], sf[qs][0][3]));
      float m1 = fmaxf(fmaxf(sf[qs][1][0], sf[qs][1][1]), fmaxf(sf[qs][1][2], sf[qs][1][3]));
      float m2 = fmaxf(fmaxf(sf[qs][2][0], sf[qs][2][1]), fmaxf(sf[qs][2][2], sf[qs][2][3]));
      float m3 = fmaxf(fmaxf(sf[qs][3][0], sf[qs][3][1]), fmaxf(sf[qs][3][2], sf[qs][3][3]));
      float mm = fmaxf(fmaxf(m0, m1), fmaxf(m2, m3));
      mm = fmaxf(mm, __shfl_xor(mm, 16));
      mm = fmaxf(mm, __shfl_xor(mm, 32));
      const float mnew = fmaxf(m_i[qs], mm);
      const float scale = exp2f(m_i[qs] - mnew);
      float rs = 0.f;
#pragma unroll
      for (int sc = 0; sc < 4; ++sc) {
#pragma unroll
        for (int i = 0; i < 4; ++i) {
          const float pv = exp2f(sf[qs][sc][i] - mnew);
          sf[qs][sc][i] = pv;
          rs += pv;
        }
      }
      rs += __shfl_xor(rs, 16);
      rs += __shfl_xor(rs, 32);
      m_i[qs] = mnew;
      s_i[qs] = s_i[qs] * scale + rs;
#pragma unroll
      for (int i = 0; i < 4; ++i) {
        const float sbc = __shfl(scale, 4 * lgrp + i);
#pragma unroll
        for (int d0 = 0; d0 < 4; ++d0) o[qs][d0][i] *= sbc;
      }
#pragma unroll
      for (int sc = 0; sc < 4; ++sc) {
        union { unsigned u[2]; s16x4 v; } tmp;
        tmp.u[0] = cvt_pk_bf16(sf[qs][sc][0], sf[qs][sc][1]);
        tmp.u[1] = cvt_pk_bf16(sf[qs][sc][2], sf[qs][sc][3]);
        pa[qs][sc] = tmp.v;
      }
    }
    // PV: O[q][d] += sum_sc P_frag[sc] x V_frag[sc] (16x16x16)
#pragma unroll
    for (int d0 = 0; d0 < 4; ++d0) {
#pragma unroll
      for (int sc = 0; sc < 4; ++sc) {
        o[0][d0] = mfma16(pa[0][sc], vb[d0][sc], o[0][d0]);
        o[1][d0] = mfma16(pa[1][sc], vb[d0][sc], o[1][d0]);
      }
    }
  }

  // ---- combine the 4 per-wave partials ----
  mshare[wid][0][lrow] = m_i[0];
  mshare[wid][1][lrow] = m_i[1];
  __syncthreads();
#pragma unroll
  for (int qs = 0; qs < 2; ++qs) {
    const float gm = fmaxf(fmaxf(mshare[0][qs][lrow], mshare[1][qs][lrow]),
                           fmaxf(mshare[2][qs][lrow], mshare[3][qs][lrow]));
    const float f = exp2f(m_i[qs] - gm);
    sshare[wid][qs][lrow] = s_i[qs] * f;
#pragma unroll
    for (int i = 0; i < 4; ++i) {
      const float fb = __shfl(f, 4 * lgrp + i);
#pragma unroll
      for (int d0 = 0; d0 < 4; ++d0)
        o_lds[wid][qs * 16 + lgrp * 4 + i][d0 * 16 + lrow] = o[qs][d0][i] * fb;
    }
  }
  __syncthreads();
  // ---- final reduce + write: thread t -> q = t>>3, 8 d-values ----
  const int t = wid * 64 + lane;
  const int q = t >> 3;
  const int d8 = (t & 7) * 8;
  const int qss = q >> 4, qr = q & 15;
  const float S = sshare[0][qss][qr] + sshare[1][qss][qr] +
                  sshare[2][qss][qr] + sshare[3][qss][qr];
  const float invS = 1.0f / S;
  short8 wv;
#pragma unroll
  for (int jj = 0; jj < 8; ++jj) {
    const float acc = o_lds[0][q][d8 + jj] + o_lds[1][q][d8 + jj] +
                      o_lds[2][q][d8 + jj] + o_lds[3][q][d8 + jj];
    wv[jj] = (short)f2bf(acc * invS);
  }
  *(short8*)(outp + (long)(q0 + q) * C_DIM + d8) = wv;
  __syncthreads();                            // protect LDS reuse by next tile
}

__global__ __launch_bounds__(256) void attn_fwd(
    const unsigned short* __restrict__ Qb,
    const unsigned short* __restrict__ Kb,
    const unsigned short* __restrict__ Vt,
    unsigned short* __restrict__ attn) {
  __shared__ float o_lds[4][32][68];
  __shared__ float mshare[4][2][16];
  __shared__ float sshare[4][2][16];
  const int bid = (int)blockIdx.x;
  const int xcd = bid & 7;
  const int j = bid >> 3;                 // 0..127
  const int bh = xcd * 4 + (j & 3);       // 4 heads per XCD -> KV in XCD L2
  const int p = j >> 2;                   // 0..31 pair index
  const int b = bh >> 4, h = bh & 15;
  const int wid = (int)threadIdx.x >> 6;
  const int lane = (int)threadIdx.x & 63;
  const int lrow = lane & 15, lgrp = lane >> 4;

  const unsigned short* Qh = Qb + (long)bh * T_LEN * HD;
  const unsigned short* Kh = Kb + (long)bh * T_LEN * HD;
  const unsigned short* Vh = Vt + (long)bh * HD * T_LEN;
  unsigned short* outp = attn + (long)b * T_LEN * C_DIM + h * HD;

  // long tile first (63-p), then short tile (p): ~33 steps total per block
  attn_tile(Qh, Kh, Vh, outp, (63 - p) * 32, wid, lane, lrow, lgrp, o_lds, mshare, sshare);
  attn_tile(Qh, Kh, Vh, outp, p * 32,        wid, lane, lrow, lgrp, o_lds, mshare, sshare);
}

extern "C" void kernel_launch(void* const* d_in, const int* in_sizes, int n_in,
                              void* d_out, int out_size, void* d_ws, size_t ws_size,
                              hipStream_t stream) {
  const float* x     = (const float*)d_in[0];
  const float* Wqkv  = (const float*)d_in[1];
  const float* bqkv  = (const float*)d_in[2];
  const float* Wproj = (const float*)d_in[3];
  const float* bproj = (const float*)d_in[4];
  float* out = (float*)d_out;
  char* ws = (char*)d_ws;
  const size_t MB = 1024 * 1024;
  unsigned short* Qb     = (unsigned short*)(ws + 0 * MB);   // [B,N,T,D] bf16, scaled log2e/8
  unsigned short* Kb     = (unsigned short*)(ws + 8 * MB);   // [B,N,T,D]
  unsigned short* Vb     = (unsigned short*)(ws + 16 * MB);  // [B,N,T,D]
  unsigned short* Vt     = (unsigned short*)(ws + 24 * MB);  // [B,N,D,T]
  unsigned short* attn   = (unsigned short*)(ws + 32 * MB);  // [B,T,C]
  unsigned short* xbf    = (unsigned short*)(ws + 40 * MB);  // [B*T,C]
  unsigned short* Wqkvt  = (unsigned short*)(ws + 48 * MB);  // [3C,C]
  unsigned short* Wprojt = (unsigned short*)(ws + 54 * MB);  // [C,C]

  cast_x<<<4096, 256, 0, stream>>>(x, xbf);
  transpose_cast<<<dim3(48, 16), 256, 0, stream>>>(Wqkv, Wqkvt, 1024, 3072);
  transpose_cast<<<dim3(16, 16), 256, 0, stream>>>(Wproj, Wprojt, 1024, 1024);
  gemm_bt<0><<<dim3(24, 32), 256, 0, stream>>>(xbf, Wqkvt, bqkv, 4096, 3072, 1024,
                                               Qb, Kb, Vb, nullptr);
  vtrans<<<dim3(32, 32), 256, 0, stream>>>(Vb, Vt);
  attn_fwd<<<1024, 256, 0, stream>>>(Qb, Kb, Vt, attn);
  gemm_bt<1><<<dim3(8, 32), 256, 0, stream>>>(attn, Wprojt, bproj, 4096, 1024, 1024,
                                              nullptr, nullptr, nullptr, out);
}

// Round 7
// 251.074 us; speedup vs baseline: 1.1179x; 1.0723x over previous
//
#include <hip/hip_runtime.h>
#include <hip/hip_bf16.h>
#include <stdint.h>

typedef __attribute__((ext_vector_type(8))) short short8;
typedef __attribute__((ext_vector_type(4))) short s16x4;
typedef __attribute__((ext_vector_type(4))) float floatx4;
typedef __attribute__((ext_vector_type(4))) unsigned short ushortx4;

#define T_LEN 2048
#define C_DIM 1024
#define NH 16
#define HD 64

static __device__ __forceinline__ unsigned short f2bf(float f) {
  union { float f; unsigned u; } v; v.f = f;
  unsigned r = v.u + 0x7fffu + ((v.u >> 16) & 1u);
  return (unsigned short)(r >> 16);
}

static __device__ __forceinline__ void stage16(const void* g, void* l) {
  __builtin_amdgcn_global_load_lds(
      (const __attribute__((address_space(1))) void*)g,
      (__attribute__((address_space(3))) void*)l, 16, 0, 0);
}

// 16x16x16 bf16 MFMA via inline asm (A,B = 2 VGPRs each, C/D = 4; D==C in place)
static __device__ __forceinline__ floatx4 mfma16(s16x4 a, s16x4 b, floatx4 c) {
  asm("v_mfma_f32_16x16x16_bf16 %0, %1, %2, %0" : "+v"(c) : "v"(a), "v"(b));
  return c;
}
// pack 2 f32 -> 1 dword of 2 bf16 (lo = s0, hi = s1)
static __device__ __forceinline__ unsigned cvt_pk_bf16(float lo, float hi) {
  unsigned r;
  asm("v_cvt_pk_bf16_f32 %0, %1, %2" : "=v"(r) : "v"(lo), "v"(hi));
  return r;
}

// ---------------- cast x (f32 -> bf16), 4 elems/thread ----------------
__global__ __launch_bounds__(256) void cast_x(const float* __restrict__ in,
                                              unsigned short* __restrict__ out) {
  const long i = (long)(blockIdx.x * 256 + threadIdx.x) * 4;
  const float4 v = *(const float4*)(in + i);
  ushortx4 o;
  o[0] = f2bf(v.x); o[1] = f2bf(v.y); o[2] = f2bf(v.z); o[3] = f2bf(v.w);
  *(ushortx4*)(out + i) = o;
}

// ---------- transpose + cast: in [R][C] f32 -> out [C][R] bf16 ----------
__global__ __launch_bounds__(256) void transpose_cast(
    const float* __restrict__ in, unsigned short* __restrict__ out, int R, int C) {
  __shared__ unsigned short tile[64][72];
  const int r0 = blockIdx.y * 64;
  const int c0 = blockIdx.x * 64;
  const int tid = threadIdx.x;
#pragma unroll
  for (int e = 0; e < 4; ++e) {
    const int ch = e * 256 + tid;           // 1024 chunks of 4 floats
    const int r = ch >> 4, c4 = (ch & 15) * 4;
    const float4 v = *(const float4*)(in + (long)(r0 + r) * C + c0 + c4);
    tile[r][c4 + 0] = f2bf(v.x);
    tile[r][c4 + 1] = f2bf(v.y);
    tile[r][c4 + 2] = f2bf(v.z);
    tile[r][c4 + 3] = f2bf(v.w);
  }
  __syncthreads();
#pragma unroll
  for (int e = 0; e < 2; ++e) {
    const int ch = e * 256 + tid;           // 512 chunks of 8
    const int c = ch >> 3, k8 = (ch & 7) * 8;
    short8 w;
#pragma unroll
    for (int j = 0; j < 8; ++j) w[j] = (short)tile[k8 + j][c];
    *(short8*)(out + (long)(c0 + c) * R + r0 + k8) = w;
  }
}

// ---------------- GEMM: C = A[M,K] * Bt[N,K]^T + bias ----------------
// 128x128 tile, BK=32, 256 threads (4 waves, 2x2 of 64x64 subtiles).
// 2-phase pipelined: double-buffered LDS; STAGE(next) issued before compute(cur);
// one counted vmcnt(0)+barrier per K-step (T3-minimum recipe).
// MODE 0: scatter to Q/K/V head layouts (Q scaled 0.125*log2e; V written ^T), bf16 out.
// MODE 1: fp32 out row-major [M][N].
#define GSTAGE(BUF, K0) do {                                                          \
    _Pragma("unroll") for (int r = 0; r < 2; ++r) {                                   \
      const int ch = r * 256 + tid;                                                   \
      const int trow = ch >> 2, tcol = (ch & 3) * 8;                                  \
      stage16(Abase + (long)trow * K + (K0) + tcol, &As[BUF][(r * 256 + wid * 64) * 8]); \
      stage16(Bbase + (long)trow * K + (K0) + tcol, &Bs[BUF][(r * 256 + wid * 64) * 8]); \
    } } while (0)

template <int MODE>
__global__ __launch_bounds__(256) void gemm_bt(
    const unsigned short* __restrict__ A,
    const unsigned short* __restrict__ Bt,
    const float* __restrict__ bias,
    int M, int N, int K,
    unsigned short* __restrict__ q_out,
    unsigned short* __restrict__ k_out,
    unsigned short* __restrict__ v_out,
    float* __restrict__ f_out) {
  __shared__ unsigned short As[2][128 * 32];
  __shared__ unsigned short Bs[2][128 * 32];
  const int tid = threadIdx.x;
  const int lane = tid & 63;
  const int wid = tid >> 6;
  const int wr = wid >> 1, wc = wid & 1;
  const int lrow = lane & 15, lgrp = lane >> 4;
  const long row0 = (long)blockIdx.y * 128;
  const long col0 = (long)blockIdx.x * 128;

  floatx4 acc[4][4];
#pragma unroll
  for (int m = 0; m < 4; ++m)
#pragma unroll
    for (int n = 0; n < 4; ++n)
      acc[m][n] = (floatx4){0.f, 0.f, 0.f, 0.f};

  const unsigned short* Abase = A + row0 * K;
  const unsigned short* Bbase = Bt + col0 * K;
  const int NT = K >> 5;

  GSTAGE(0, 0);
  asm volatile("s_waitcnt vmcnt(0)" ::: "memory");
  __builtin_amdgcn_s_barrier();

  int cur = 0;
  for (int t = 0; t < NT - 1; ++t) {
    GSTAGE(cur ^ 1, (t + 1) * 32);          // issue next tile's loads FIRST
    short8 af[4], bf[4];
#pragma unroll
    for (int m = 0; m < 4; ++m)
      af[m] = *(const short8*)&As[cur][(wr * 64 + m * 16 + lrow) * 32 + lgrp * 8];
#pragma unroll
    for (int n = 0; n < 4; ++n)
      bf[n] = *(const short8*)&Bs[cur][(wc * 64 + n * 16 + lrow) * 32 + lgrp * 8];
    __builtin_amdgcn_s_setprio(1);
#pragma unroll
    for (int m = 0; m < 4; ++m)
#pragma unroll
      for (int n = 0; n < 4; ++n)
        acc[m][n] = __builtin_amdgcn_mfma_f32_16x16x32_bf16(af[m], bf[n], acc[m][n], 0, 0, 0);
    __builtin_amdgcn_s_setprio(0);
    asm volatile("s_waitcnt vmcnt(0)" ::: "memory");
    __builtin_amdgcn_s_barrier();
    cur ^= 1;
  }
  {                                          // last tile: no prefetch
    short8 af[4], bf[4];
#pragma unroll
    for (int m = 0; m < 4; ++m)
      af[m] = *(const short8*)&As[cur][(wr * 64 + m * 16 + lrow) * 32 + lgrp * 8];
#pragma unroll
    for (int n = 0; n < 4; ++n)
      bf[n] = *(const short8*)&Bs[cur][(wc * 64 + n * 16 + lrow) * 32 + lgrp * 8];
#pragma unroll
    for (int m = 0; m < 4; ++m)
#pragma unroll
      for (int n = 0; n < 4; ++n)
        acc[m][n] = __builtin_amdgcn_mfma_f32_16x16x32_bf16(af[m], bf[n], acc[m][n], 0, 0, 0);
  }

  if (MODE == 0) {
#pragma unroll
    for (int n = 0; n < 4; ++n) {
      const int c = (int)col0 + wc * 64 + n * 16 + lrow;
      const float bs = bias[c];
      const int sect = c >> 10;            // 0=Q 1=K 2=V
      const int h = (c & 1023) >> 6;
      const int d = c & 63;
      // fold 1/sqrt(64) AND log2(e) into Q (attn uses exp2)
      const float scl = sect == 0 ? 0.18033688011112042f : 1.0f;
#pragma unroll
      for (int m = 0; m < 4; ++m) {
#pragma unroll
        for (int i = 0; i < 4; ++i) {
          const long r = row0 + wr * 64 + m * 16 + lgrp * 4 + i;
          const long b = r >> 11;          // r / 2048
          const long t = r & 2047;
          const float val = (acc[m][n][i] + bs) * scl;
          if (sect == 2) {                 // V written transposed: [bh][D][T]
            v_out[((b * NH + h) * HD + d) * T_LEN + t] = f2bf(val);
          } else {
            unsigned short* dst = sect == 0 ? q_out : k_out;
            dst[((b * NH + h) * T_LEN + t) * HD + d] = f2bf(val);
          }
        }
      }
    }
  } else {
#pragma unroll
    for (int n = 0; n < 4; ++n) {
      const int c = (int)col0 + wc * 64 + n * 16 + lrow;
      const float bs = bias[c];
#pragma unroll
      for (int m = 0; m < 4; ++m) {
#pragma unroll
        for (int i = 0; i < 4; ++i) {
          const long r = row0 + wr * 64 + m * 16 + lgrp * 4 + i;
          f_out[r * (long)N + c] = acc[m][n][i] + bs;
        }
      }
    }
  }
}

// ------- flash attention v7: paired q-tiles, KV-split 4 waves, defer-max -------
// Block handles TWO q-tiles (qtA = 63-p long, qtB = p short); waves split KV steps.
// Swapped QK^T -> lane-local softmax (exp2, exact defer-max); reg-direct PV.
// Grid 1-D XCD-clustered (4 heads/XCD => KV stays in XCD L2).
__device__ __forceinline__ void attn_tile(
    const unsigned short* __restrict__ Qh,
    const unsigned short* __restrict__ Kh,
    const unsigned short* __restrict__ Vh,
    unsigned short* __restrict__ outp,    // attn + b*T*C + h*HD
    int q0, int wid, int lane, int lrow, int lgrp,
    float (*o_lds)[32][68], float (*mshare)[2][16], float (*sshare)[2][16]) {
  const int nsteps = (q0 + 32 + 63) >> 6;     // ceil((q0+32)/64)

  // Q fragments (B operand of swapped QK^T): [qsub][kk]
  short8 aq[2][2];
#pragma unroll
  for (int qs = 0; qs < 2; ++qs)
#pragma unroll
    for (int kk = 0; kk < 2; ++kk)
      aq[qs][kk] = *(const short8*)(Qh + (long)(q0 + qs * 16 + lrow) * HD + kk * 32 + lgrp * 8);

  float m_i[2] = {-1e30f, -1e30f};
  float s_i[2] = {0.f, 0.f};
  floatx4 o[2][4];                            // O[q=16qs+4lg+i][d=16d0+lrow]
#pragma unroll
  for (int qs = 0; qs < 2; ++qs)
#pragma unroll
    for (int d0 = 0; d0 < 4; ++d0) o[qs][d0] = (floatx4){0.f, 0.f, 0.f, 0.f};

  for (int st = wid; st < nsteps; st += 4) {
    const int s0 = st * 64;
    // hoisted K loads (8x16B) and V loads (16x8B): pipeline together
    short8 kf[4][2];
#pragma unroll
    for (int sc = 0; sc < 4; ++sc)
#pragma unroll
      for (int kk = 0; kk < 2; ++kk)
        kf[sc][kk] = *(const short8*)(Kh + (long)(s0 + sc * 16 + lrow) * HD + kk * 32 + lgrp * 8);
    s16x4 vb[4][4];                           // [d0][sc]
#pragma unroll
    for (int d0 = 0; d0 < 4; ++d0)
#pragma unroll
      for (int sc = 0; sc < 4; ++sc)
        vb[d0][sc] = *(const s16x4*)(Vh + (long)(d0 * 16 + lrow) * T_LEN + s0 + sc * 16 + lgrp * 4);
    // QK^T (swapped): sf[qs][sc][i] = S[q=q0+16qs+lrow][s=s0+16sc+4lg+i]
    floatx4 sf[2][4];
#pragma unroll
    for (int qs = 0; qs < 2; ++qs)
#pragma unroll
      for (int sc = 0; sc < 4; ++sc) sf[qs][sc] = (floatx4){0.f, 0.f, 0.f, 0.f};
    __builtin_amdgcn_s_setprio(1);
#pragma unroll
    for (int sc = 0; sc < 4; ++sc) {
#pragma unroll
      for (int kk = 0; kk < 2; ++kk) {
        sf[0][sc] = __builtin_amdgcn_mfma_f32_16x16x32_bf16(kf[sc][kk], aq[0][kk], sf[0][sc], 0, 0, 0);
        sf[1][sc] = __builtin_amdgcn_mfma_f32_16x16x32_bf16(kf[sc][kk], aq[1][kk], sf[1][sc], 0, 0, 0);
      }
    }
    __builtin_amdgcn_s_setprio(0);
    // causal mask (diagonal step only)
    if (s0 + 64 > q0) {
#pragma unroll
      for (int qs = 0; qs < 2; ++qs) {
        const int q = q0 + qs * 16 + lrow;
#pragma unroll
        for (int sc = 0; sc < 4; ++sc) {
#pragma unroll
          for (int i = 0; i < 4; ++i) {
            const int s = s0 + sc * 16 + lgrp * 4 + i;
            if (s > q) sf[qs][sc][i] = -1e30f;
          }
        }
      }
    }
    // online softmax: row lane-local (16 vals) + 2 shfl_xor; exp2 domain.
    // Exact defer-max: if no row in the wave grew its max, scale==1 -> skip rescale.
    s16x4 pa[2][4];
#pragma unroll
    for (int qs = 0; qs < 2; ++qs) {
      float m0 = fmaxf(fmaxf(sf[qs][0][0], sf[qs][0][1]), fmaxf(sf[qs][0][2], sf[qs][0][3]));
      float m1 = fmaxf(fmaxf(sf[qs][1][0], sf[qs][1][1]), fmaxf(sf[qs][1][2], sf[qs][1][3]));
      float m2 = fmaxf(fmaxf(sf[qs][2][0], sf[qs][2][1]), fmaxf(sf[qs][2][2], sf[qs][2][3]));
      float m3 = fmaxf(fmaxf(sf[qs][3][0], sf[qs][3][1]), fmaxf(sf[qs][3][2], sf[qs][3][3]));
      float mm = fmaxf(fmaxf(m0, m1), fmaxf(m2, m3));
      mm = fmaxf(mm, __shfl_xor(mm, 16));
      mm = fmaxf(mm, __shfl_xor(mm, 32));
      const int grow = !__all(mm <= m_i[qs]); // wave-uniform branch
      float scale = 1.0f;
      if (grow) {
        const float mnew = fmaxf(m_i[qs], mm);
        scale = exp2f(m_i[qs] - mnew);
        m_i[qs] = mnew;
      }
      float rs = 0.f;
#pragma unroll
      for (int sc = 0; sc < 4; ++sc) {
#pragma unroll
        for (int i = 0; i < 4; ++i) {
          const float pv = exp2f(sf[qs][sc][i] - m_i[qs]);
          sf[qs][sc][i] = pv;
          rs += pv;
        }
      }
      rs += __shfl_xor(rs, 16);
      rs += __shfl_xor(rs, 32);
      s_i[qs] = s_i[qs] * scale + rs;
      if (grow) {
#pragma unroll
        for (int i = 0; i < 4; ++i) {
          const float sbc = __shfl(scale, 4 * lgrp + i);
#pragma unroll
          for (int d0 = 0; d0 < 4; ++d0) o[qs][d0][i] *= sbc;
        }
      }
#pragma unroll
      for (int sc = 0; sc < 4; ++sc) {
        union { unsigned u[2]; s16x4 v; } tmp;
        tmp.u[0] = cvt_pk_bf16(sf[qs][sc][0], sf[qs][sc][1]);
        tmp.u[1] = cvt_pk_bf16(sf[qs][sc][2], sf[qs][sc][3]);
        pa[qs][sc] = tmp.v;
      }
    }
    // PV: O[q][d] += sum_sc P_frag[sc] x V_frag[sc] (16x16x16)
    __builtin_amdgcn_s_setprio(1);
#pragma unroll
    for (int d0 = 0; d0 < 4; ++d0) {
#pragma unroll
      for (int sc = 0; sc < 4; ++sc) {
        o[0][d0] = mfma16(pa[0][sc], vb[d0][sc], o[0][d0]);
        o[1][d0] = mfma16(pa[1][sc], vb[d0][sc], o[1][d0]);
      }
    }
    __builtin_amdgcn_s_setprio(0);
  }

  // ---- combine the 4 per-wave partials ----
  mshare[wid][0][lrow] = m_i[0];
  mshare[wid][1][lrow] = m_i[1];
  __syncthreads();
#pragma unroll
  for (int qs = 0; qs < 2; ++qs) {
    const float gm = fmaxf(fmaxf(mshare[0][qs][lrow], mshare[1][qs][lrow]),
                           fmaxf(mshare[2][qs][lrow], mshare[3][qs][lrow]));
    const float f = exp2f(m_i[qs] - gm);
    sshare[wid][qs][lrow] = s_i[qs] * f;
#pragma unroll
    for (int i = 0; i < 4; ++i) {
      const float fb = __shfl(f, 4 * lgrp + i);
#pragma unroll
      for (int d0 = 0; d0 < 4; ++d0)
        o_lds[wid][qs * 16 + lgrp * 4 + i][d0 * 16 + lrow] = o[qs][d0][i] * fb;
    }
  }
  __syncthreads();
  // ---- final reduce + write: thread t -> q = t>>3, 8 d-values ----
  const int t = wid * 64 + lane;
  const int q = t >> 3;
  const int d8 = (t & 7) * 8;
  const int qss = q >> 4, qr = q & 15;
  const float S = sshare[0][qss][qr] + sshare[1][qss][qr] +
                  sshare[2][qss][qr] + sshare[3][qss][qr];
  const float invS = 1.0f / S;
  short8 wv;
#pragma unroll
  for (int jj = 0; jj < 8; ++jj) {
    const float acc = o_lds[0][q][d8 + jj] + o_lds[1][q][d8 + jj] +
                      o_lds[2][q][d8 + jj] + o_lds[3][q][d8 + jj];
    wv[jj] = (short)f2bf(acc * invS);
  }
  *(short8*)(outp + (long)(q0 + q) * C_DIM + d8) = wv;
  __syncthreads();                            // protect LDS reuse by next tile
}

__global__ __launch_bounds__(256) void attn_fwd(
    const unsigned short* __restrict__ Qb,
    const unsigned short* __restrict__ Kb,
    const unsigned short* __restrict__ Vt,
    unsigned short* __restrict__ attn) {
  __shared__ float o_lds[4][32][68];
  __shared__ float mshare[4][2][16];
  __shared__ float sshare[4][2][16];
  const int bid = (int)blockIdx.x;
  const int xcd = bid & 7;
  const int j = bid >> 3;                 // 0..127
  const int bh = xcd * 4 + (j & 3);       // 4 heads per XCD -> KV in XCD L2
  const int p = j >> 2;                   // 0..31 pair index
  const int b = bh >> 4, h = bh & 15;
  const int wid = (int)threadIdx.x >> 6;
  const int lane = (int)threadIdx.x & 63;
  const int lrow = lane & 15, lgrp = lane >> 4;

  const unsigned short* Qh = Qb + (long)bh * T_LEN * HD;
  const unsigned short* Kh = Kb + (long)bh * T_LEN * HD;
  const unsigned short* Vh = Vt + (long)bh * HD * T_LEN;
  unsigned short* outp = attn + (long)b * T_LEN * C_DIM + h * HD;

  // long tile first (63-p), then short tile (p): ~33 steps total per block
  attn_tile(Qh, Kh, Vh, outp, (63 - p) * 32, wid, lane, lrow, lgrp, o_lds, mshare, sshare);
  attn_tile(Qh, Kh, Vh, outp, p * 32,        wid, lane, lrow, lgrp, o_lds, mshare, sshare);
}

extern "C" void kernel_launch(void* const* d_in, const int* in_sizes, int n_in,
                              void* d_out, int out_size, void* d_ws, size_t ws_size,
                              hipStream_t stream) {
  const float* x     = (const float*)d_in[0];
  const float* Wqkv  = (const float*)d_in[1];
  const float* bqkv  = (const float*)d_in[2];
  const float* Wproj = (const float*)d_in[3];
  const float* bproj = (const float*)d_in[4];
  float* out = (float*)d_out;
  char* ws = (char*)d_ws;
  const size_t MB = 1024 * 1024;
  unsigned short* Qb     = (unsigned short*)(ws + 0 * MB);   // [B,N,T,D] bf16, scaled log2e/8
  unsigned short* Kb     = (unsigned short*)(ws + 8 * MB);   // [B,N,T,D]
  unsigned short* Vt     = (unsigned short*)(ws + 24 * MB);  // [B,N,D,T] (written ^T by GEMM)
  unsigned short* attn   = (unsigned short*)(ws + 32 * MB);  // [B,T,C]
  unsigned short* xbf    = (unsigned short*)(ws + 40 * MB);  // [B*T,C]
  unsigned short* Wqkvt  = (unsigned short*)(ws + 48 * MB);  // [3C,C]
  unsigned short* Wprojt = (unsigned short*)(ws + 54 * MB);  // [C,C]

  cast_x<<<4096, 256, 0, stream>>>(x, xbf);
  transpose_cast<<<dim3(48, 16), 256, 0, stream>>>(Wqkv, Wqkvt, 1024, 3072);
  transpose_cast<<<dim3(16, 16), 256, 0, stream>>>(Wproj, Wprojt, 1024, 1024);
  gemm_bt<0><<<dim3(24, 32), 256, 0, stream>>>(xbf, Wqkvt, bqkv, 4096, 3072, 1024,
                                               Qb, Kb, Vt, nullptr);
  attn_fwd<<<1024, 256, 0, stream>>>(Qb, Kb, Vt, attn);
  gemm_bt<1><<<dim3(8, 32), 256, 0, stream>>>(attn, Wprojt, bproj, 4096, 1024, 1024,
                                              nullptr, nullptr, nullptr, out);
}

// Round 9
// 245.142 us; speedup vs baseline: 1.1450x; 1.0242x over previous
//
#include <hip/hip_runtime.h>
#include <hip/hip_bf16.h>
#include <stdint.h>

typedef __attribute__((ext_vector_type(8))) short short8;
typedef __attribute__((ext_vector_type(4))) short s16x4;
typedef __attribute__((ext_vector_type(4))) float floatx4;
typedef __attribute__((ext_vector_type(4))) unsigned short ushortx4;

#define T_LEN 2048
#define C_DIM 1024
#define NH 16
#define HD 64

static __device__ __forceinline__ unsigned short f2bf(float f) {
  union { float f; unsigned u; } v; v.f = f;
  unsigned r = v.u + 0x7fffu + ((v.u >> 16) & 1u);
  return (unsigned short)(r >> 16);
}

static __device__ __forceinline__ void stage16(const void* g, void* l) {
  __builtin_amdgcn_global_load_lds(
      (const __attribute__((address_space(1))) void*)g,
      (__attribute__((address_space(3))) void*)l, 16, 0, 0);
}

// 16x16x16 bf16 MFMA via inline asm (A,B = 2 VGPRs each, C/D = 4; D==C in place)
static __device__ __forceinline__ floatx4 mfma16(s16x4 a, s16x4 b, floatx4 c) {
  asm("v_mfma_f32_16x16x16_bf16 %0, %1, %2, %0" : "+v"(c) : "v"(a), "v"(b));
  return c;
}
// pack 2 f32 -> 1 dword of 2 bf16 (lo = s0, hi = s1)
static __device__ __forceinline__ unsigned cvt_pk_bf16(float lo, float hi) {
  unsigned r;
  asm("v_cvt_pk_bf16_f32 %0, %1, %2" : "=v"(r) : "v"(lo), "v"(hi));
  return r;
}

// ---------- transpose + cast body: in [R][C] f32 -> out [C][R] bf16 ----------
static __device__ __forceinline__ void tc_body(
    const float* __restrict__ in, unsigned short* __restrict__ out,
    int R, int C, int bx, int by, int tid, unsigned short (*tile)[72]) {
  const int r0 = by * 64;
  const int c0 = bx * 64;
#pragma unroll
  for (int e = 0; e < 4; ++e) {
    const int ch = e * 256 + tid;           // 1024 chunks of 4 floats
    const int r = ch >> 4, c4 = (ch & 15) * 4;
    const float4 v = *(const float4*)(in + (long)(r0 + r) * C + c0 + c4);
    tile[r][c4 + 0] = f2bf(v.x);
    tile[r][c4 + 1] = f2bf(v.y);
    tile[r][c4 + 2] = f2bf(v.z);
    tile[r][c4 + 3] = f2bf(v.w);
  }
  __syncthreads();
#pragma unroll
  for (int e = 0; e < 2; ++e) {
    const int ch = e * 256 + tid;           // 512 chunks of 8
    const int c = ch >> 3, k8 = (ch & 7) * 8;
    short8 w;
#pragma unroll
    for (int j = 0; j < 8; ++j) w[j] = (short)tile[k8 + j][c];
    *(short8*)(out + (long)(c0 + c) * R + r0 + k8) = w;
  }
}

// ---- fused prep: cast x (blocks 0..4095), W_qkv^T (4096..4863), W_proj^T (4864..5119) ----
__global__ __launch_bounds__(256) void prep(
    const float* __restrict__ x, unsigned short* __restrict__ xbf,
    const float* __restrict__ Wqkv, unsigned short* __restrict__ Wqkvt,
    const float* __restrict__ Wproj, unsigned short* __restrict__ Wprojt) {
  __shared__ unsigned short tile[64][72];
  const int bid = (int)blockIdx.x;
  const int tid = (int)threadIdx.x;
  if (bid < 4096) {
    const long i = ((long)bid * 256 + tid) * 4;
    const float4 v = *(const float4*)(x + i);
    ushortx4 o;
    o[0] = f2bf(v.x); o[1] = f2bf(v.y); o[2] = f2bf(v.z); o[3] = f2bf(v.w);
    *(ushortx4*)(xbf + i) = o;
  } else if (bid < 4096 + 768) {
    const int t = bid - 4096;
    tc_body(Wqkv, Wqkvt, 1024, 3072, t % 48, t / 48, tid, tile);
  } else {
    const int t = bid - 4864;
    tc_body(Wproj, Wprojt, 1024, 1024, t % 16, t / 16, tid, tile);
  }
}

// ---------------- GEMM: C = A[M,K] * Bt[N,K]^T + bias ----------------
// 128x128 tile, BK=32, 256 threads (4 waves, 2x2 of 64x64 subtiles).
// 2-phase pipelined dbuf LDS; 1-D grid with bijective XCD-chunked swizzle (T1).
// MODE 0: scatter to Q/K/V head layouts (Q scaled 0.125*log2e; V written ^T), bf16 out.
// MODE 1: fp32 out row-major [M][N].
#define GSTAGE(BUF, K0) do {                                                          \
    _Pragma("unroll") for (int r = 0; r < 2; ++r) {                                   \
      const int ch = r * 256 + tid;                                                   \
      const int trow = ch >> 2, tcol = (ch & 3) * 8;                                  \
      stage16(Abase + (long)trow * K + (K0) + tcol, &As[BUF][(r * 256 + wid * 64) * 8]); \
      stage16(Bbase + (long)trow * K + (K0) + tcol, &Bs[BUF][(r * 256 + wid * 64) * 8]); \
    } } while (0)

template <int MODE>
__global__ __launch_bounds__(256) void gemm_bt(
    const unsigned short* __restrict__ A,
    const unsigned short* __restrict__ Bt,
    const float* __restrict__ bias,
    int M, int N, int K, int nbx,
    unsigned short* __restrict__ q_out,
    unsigned short* __restrict__ k_out,
    unsigned short* __restrict__ v_out,
    float* __restrict__ f_out) {
  __shared__ unsigned short As[2][128 * 32];
  __shared__ unsigned short Bs[2][128 * 32];
  const int tid = threadIdx.x;
  const int lane = tid & 63;
  const int wid = tid >> 6;
  const int wr = wid >> 1, wc = wid & 1;
  const int lrow = lane & 15, lgrp = lane >> 4;
  // XCD-chunked bijective swizzle (gridDim.x % 8 == 0)
  const int bid = (int)blockIdx.x;
  const int v = (bid & 7) * ((int)gridDim.x >> 3) + (bid >> 3);
  const long row0 = (long)(v / nbx) * 128;
  const long col0 = (long)(v % nbx) * 128;

  floatx4 acc[4][4];
#pragma unroll
  for (int m = 0; m < 4; ++m)
#pragma unroll
    for (int n = 0; n < 4; ++n)
      acc[m][n] = (floatx4){0.f, 0.f, 0.f, 0.f};

  const unsigned short* Abase = A + row0 * K;
  const unsigned short* Bbase = Bt + col0 * K;
  const int NT = K >> 5;

  GSTAGE(0, 0);
  asm volatile("s_waitcnt vmcnt(0)" ::: "memory");
  __builtin_amdgcn_s_barrier();

  int cur = 0;
  for (int t = 0; t < NT - 1; ++t) {
    GSTAGE(cur ^ 1, (t + 1) * 32);          // issue next tile's loads FIRST
    short8 af[4], bf[4];
#pragma unroll
    for (int m = 0; m < 4; ++m)
      af[m] = *(const short8*)&As[cur][(wr * 64 + m * 16 + lrow) * 32 + lgrp * 8];
#pragma unroll
    for (int n = 0; n < 4; ++n)
      bf[n] = *(const short8*)&Bs[cur][(wc * 64 + n * 16 + lrow) * 32 + lgrp * 8];
    __builtin_amdgcn_s_setprio(1);
#pragma unroll
    for (int m = 0; m < 4; ++m)
#pragma unroll
      for (int n = 0; n < 4; ++n)
        acc[m][n] = __builtin_amdgcn_mfma_f32_16x16x32_bf16(af[m], bf[n], acc[m][n], 0, 0, 0);
    __builtin_amdgcn_s_setprio(0);
    asm volatile("s_waitcnt vmcnt(0)" ::: "memory");
    __builtin_amdgcn_s_barrier();
    cur ^= 1;
  }
  {                                          // last tile: no prefetch
    short8 af[4], bf[4];
#pragma unroll
    for (int m = 0; m < 4; ++m)
      af[m] = *(const short8*)&As[cur][(wr * 64 + m * 16 + lrow) * 32 + lgrp * 8];
#pragma unroll
    for (int n = 0; n < 4; ++n)
      bf[n] = *(const short8*)&Bs[cur][(wc * 64 + n * 16 + lrow) * 32 + lgrp * 8];
#pragma unroll
    for (int m = 0; m < 4; ++m)
#pragma unroll
      for (int n = 0; n < 4; ++n)
        acc[m][n] = __builtin_amdgcn_mfma_f32_16x16x32_bf16(af[m], bf[n], acc[m][n], 0, 0, 0);
  }

  if (MODE == 0) {
#pragma unroll
    for (int n = 0; n < 4; ++n) {
      const int c = (int)col0 + wc * 64 + n * 16 + lrow;
      const float bs = bias[c];
      const int sect = c >> 10;            // 0=Q 1=K 2=V
      const int h = (c & 1023) >> 6;
      const int d = c & 63;
      // fold 1/sqrt(64) AND log2(e) into Q (attn uses exp2)
      const float scl = sect == 0 ? 0.18033688011112042f : 1.0f;
#pragma unroll
      for (int m = 0; m < 4; ++m) {
#pragma unroll
        for (int i = 0; i < 4; ++i) {
          const long r = row0 + wr * 64 + m * 16 + lgrp * 4 + i;
          const long b = r >> 11;          // r / 2048
          const long t = r & 2047;
          const float val = (acc[m][n][i] + bs) * scl;
          if (sect == 2) {                 // V written transposed: [bh][D][T]
            v_out[((b * NH + h) * HD + d) * T_LEN + t] = f2bf(val);
          } else {
            unsigned short* dst = sect == 0 ? q_out : k_out;
            dst[((b * NH + h) * T_LEN + t) * HD + d] = f2bf(val);
          }
        }
      }
    }
  } else {
#pragma unroll
    for (int n = 0; n < 4; ++n) {
      const int c = (int)col0 + wc * 64 + n * 16 + lrow;
      const float bs = bias[c];
#pragma unroll
      for (int m = 0; m < 4; ++m) {
#pragma unroll
        for (int i = 0; i < 4; ++i) {
          const long r = row0 + wr * 64 + m * 16 + lgrp * 4 + i;
          f_out[r * (long)N + c] = acc[m][n][i] + bs;
        }
      }
    }
  }
}

// ------- flash attention v8: small-LDS phased combine, 2048 blocks -------
// Block = (bh, qt): 32 q-rows, 4 waves split KV steps (wave w: steps w, w+4, ...).
// Swapped QK^T -> lane-local softmax (exp2, exact defer-max); reg-direct PV.
// Epilogue: ONE osum[32][68] buffer, 4 barrier-phased accumulations (LDS 9.7KB
// vs 35.8KB before -> co-residency becomes VGPR-bound ~5 blocks/CU, not LDS-bound 4).
// Grid 1-D XCD-clustered (4 heads/XCD => KV in XCD L2), qt reversed (long first).
__global__ __launch_bounds__(256) void attn_fwd(
    const unsigned short* __restrict__ Qb,
    const unsigned short* __restrict__ Kb,
    const unsigned short* __restrict__ Vt,
    unsigned short* __restrict__ attn) {
  __shared__ float osum[32][68];
  __shared__ float mshare[4][2][16];
  __shared__ float sshare[4][2][16];
  const int bid = (int)blockIdx.x;
  const int xcd = bid & 7;
  const int j = bid >> 3;                 // 0..255
  const int bh = xcd * 4 + (j & 3);       // 4 heads per XCD -> KV in XCD L2
  const int qt = 63 - (j >> 2);           // reversed: long blocks first
  const int b = bh >> 4, h = bh & 15;
  const int wid = (int)threadIdx.x >> 6;
  const int lane = (int)threadIdx.x & 63;
  const int lrow = lane & 15, lgrp = lane >> 4;
  const int q0 = qt * 32;
  const int nsteps = (q0 + 32 + 63) >> 6; // ceil((q0+32)/64)

  const unsigned short* Qh = Qb + (long)bh * T_LEN * HD;
  const unsigned short* Kh = Kb + (long)bh * T_LEN * HD;
  const unsigned short* Vh = Vt + (long)bh * HD * T_LEN;

  // Q fragments (B operand of swapped QK^T): [qsub][kk]
  short8 aq[2][2];
#pragma unroll
  for (int qs = 0; qs < 2; ++qs)
#pragma unroll
    for (int kk = 0; kk < 2; ++kk)
      aq[qs][kk] = *(const short8*)(Qh + (long)(q0 + qs * 16 + lrow) * HD + kk * 32 + lgrp * 8);

  float m_i[2] = {-1e30f, -1e30f};
  float s_i[2] = {0.f, 0.f};
  floatx4 o[2][4];                        // O[q=16qs+4lg+i][d=16d0+lrow]
#pragma unroll
  for (int qs = 0; qs < 2; ++qs)
#pragma unroll
    for (int d0 = 0; d0 < 4; ++d0) o[qs][d0] = (floatx4){0.f, 0.f, 0.f, 0.f};

  for (int st = wid; st < nsteps; st += 4) {
    const int s0 = st * 64;
    // hoisted K loads (8x16B) and V loads (16x8B): pipeline together
    short8 kf[4][2];
#pragma unroll
    for (int sc = 0; sc < 4; ++sc)
#pragma unroll
      for (int kk = 0; kk < 2; ++kk)
        kf[sc][kk] = *(const short8*)(Kh + (long)(s0 + sc * 16 + lrow) * HD + kk * 32 + lgrp * 8);
    s16x4 vb[4][4];                       // [d0][sc]
#pragma unroll
    for (int d0 = 0; d0 < 4; ++d0)
#pragma unroll
      for (int sc = 0; sc < 4; ++sc)
        vb[d0][sc] = *(const s16x4*)(Vh + (long)(d0 * 16 + lrow) * T_LEN + s0 + sc * 16 + lgrp * 4);
    // QK^T (swapped): sf[qs][sc][i] = S[q=q0+16qs+lrow][s=s0+16sc+4lg+i]
    floatx4 sf[2][4];
#pragma unroll
    for (int qs = 0; qs < 2; ++qs)
#pragma unroll
      for (int sc = 0; sc < 4; ++sc) sf[qs][sc] = (floatx4){0.f, 0.f, 0.f, 0.f};
    __builtin_amdgcn_s_setprio(1);
#pragma unroll
    for (int sc = 0; sc < 4; ++sc) {
#pragma unroll
      for (int kk = 0; kk < 2; ++kk) {
        sf[0][sc] = __builtin_amdgcn_mfma_f32_16x16x32_bf16(kf[sc][kk], aq[0][kk], sf[0][sc], 0, 0, 0);
        sf[1][sc] = __builtin_amdgcn_mfma_f32_16x16x32_bf16(kf[sc][kk], aq[1][kk], sf[1][sc], 0, 0, 0);
      }
    }
    __builtin_amdgcn_s_setprio(0);
    // causal mask (diagonal step only)
    if (s0 + 64 > q0) {
#pragma unroll
      for (int qs = 0; qs < 2; ++qs) {
        const int q = q0 + qs * 16 + lrow;
#pragma unroll
        for (int sc = 0; sc < 4; ++sc) {
#pragma unroll
          for (int i = 0; i < 4; ++i) {
            const int s = s0 + sc * 16 + lgrp * 4 + i;
            if (s > q) sf[qs][sc][i] = -1e30f;
          }
        }
      }
    }
    // online softmax: row lane-local (16 vals) + 2 shfl_xor; exp2 domain.
    // Exact defer-max: if no row in the wave grew its max, scale==1 -> skip rescale.
    s16x4 pa[2][4];
#pragma unroll
    for (int qs = 0; qs < 2; ++qs) {
      float m0 = fmaxf(fmaxf(sf[qs][0][0], sf[qs][0][1]), fmaxf(sf[qs][0][2], sf[qs][0][3]));
      float m1 = fmaxf(fmaxf(sf[qs][1][0], sf[qs][1][1]), fmaxf(sf[qs][1][2], sf[qs][1][3]));
      float m2 = fmaxf(fmaxf(sf[qs][2][0], sf[qs][2][1]), fmaxf(sf[qs][2][2], sf[qs][2][3]));
      float m3 = fmaxf(fmaxf(sf[qs][3][0], sf[qs][3][1]), fmaxf(sf[qs][3][2], sf[qs][3][3]));
      float mm = fmaxf(fmaxf(m0, m1), fmaxf(m2, m3));
      mm = fmaxf(mm, __shfl_xor(mm, 16));
      mm = fmaxf(mm, __shfl_xor(mm, 32));
      const int grow = !__all(mm <= m_i[qs]); // wave-uniform branch
      float scale = 1.0f;
      if (grow) {
        const float mnew = fmaxf(m_i[qs], mm);
        scale = exp2f(m_i[qs] - mnew);
        m_i[qs] = mnew;
      }
      float rs = 0.f;
#pragma unroll
      for (int sc = 0; sc < 4; ++sc) {
#pragma unroll
        for (int i = 0; i < 4; ++i) {
          const float pv = exp2f(sf[qs][sc][i] - m_i[qs]);
          sf[qs][sc][i] = pv;
          rs += pv;
        }
      }
      rs += __shfl_xor(rs, 16);
      rs += __shfl_xor(rs, 32);
      s_i[qs] = s_i[qs] * scale + rs;
      if (grow) {
#pragma unroll
        for (int i = 0; i < 4; ++i) {
          const float sbc = __shfl(scale, 4 * lgrp + i);
#pragma unroll
          for (int d0 = 0; d0 < 4; ++d0) o[qs][d0][i] *= sbc;
        }
      }
#pragma unroll
      for (int sc = 0; sc < 4; ++sc) {
        union { unsigned u[2]; s16x4 v; } tmp;
        tmp.u[0] = cvt_pk_bf16(sf[qs][sc][0], sf[qs][sc][1]);
        tmp.u[1] = cvt_pk_bf16(sf[qs][sc][2], sf[qs][sc][3]);
        pa[qs][sc] = tmp.v;
      }
    }
    // PV: O[q][d] += sum_sc P_frag[sc] x V_frag[sc] (16x16x16)
    __builtin_amdgcn_s_setprio(1);
#pragma unroll
    for (int d0 = 0; d0 < 4; ++d0) {
#pragma unroll
      for (int sc = 0; sc < 4; ++sc) {
        o[0][d0] = mfma16(pa[0][sc], vb[d0][sc], o[0][d0]);
        o[1][d0] = mfma16(pa[1][sc], vb[d0][sc], o[1][d0]);
      }
    }
    __builtin_amdgcn_s_setprio(0);
  }

  // ---- combine the 4 per-wave partials (phased, single osum buffer) ----
  mshare[wid][0][lrow] = m_i[0];
  mshare[wid][1][lrow] = m_i[1];
  __syncthreads();
  float fb2[2][4];
#pragma unroll
  for (int qs = 0; qs < 2; ++qs) {
    const float gm = fmaxf(fmaxf(mshare[0][qs][lrow], mshare[1][qs][lrow]),
                           fmaxf(mshare[2][qs][lrow], mshare[3][qs][lrow]));
    const float f = exp2f(m_i[qs] - gm);
    sshare[wid][qs][lrow] = s_i[qs] * f;
#pragma unroll
    for (int i = 0; i < 4; ++i) fb2[qs][i] = __shfl(f, 4 * lgrp + i);
  }
#pragma unroll
  for (int w = 0; w < 4; ++w) {
    if (wid == w) {
#pragma unroll
      for (int qs = 0; qs < 2; ++qs) {
#pragma unroll
        for (int i = 0; i < 4; ++i) {
#pragma unroll
          for (int d0 = 0; d0 < 4; ++d0) {
            const int qq = qs * 16 + lgrp * 4 + i;
            const int dd = d0 * 16 + lrow;
            const float vv = o[qs][d0][i] * fb2[qs][i];
            if (w == 0) osum[qq][dd] = vv;
            else        osum[qq][dd] += vv;
          }
        }
      }
    }
    __syncthreads();
  }
  // ---- final reduce + write: thread t -> q = t>>3, 8 d-values ----
  const int t = wid * 64 + lane;
  const int q = t >> 3;
  const int d8 = (t & 7) * 8;
  const int qss = q >> 4, qr = q & 15;
  const float S = sshare[0][qss][qr] + sshare[1][qss][qr] +
                  sshare[2][qss][qr] + sshare[3][qss][qr];
  const float invS = 1.0f / S;
  short8 wv;
#pragma unroll
  for (int jj = 0; jj < 8; ++jj)
    wv[jj] = (short)f2bf(osum[q][d8 + jj] * invS);
  *(short8*)(attn + (long)(b * T_LEN + q0 + q) * C_DIM + h * HD + d8) = wv;
}

extern "C" void kernel_launch(void* const* d_in, const int* in_sizes, int n_in,
                              void* d_out, int out_size, void* d_ws, size_t ws_size,
                              hipStream_t stream) {
  const float* x     = (const float*)d_in[0];
  const float* Wqkv  = (const float*)d_in[1];
  const float* bqkv  = (const float*)d_in[2];
  const float* Wproj = (const float*)d_in[3];
  const float* bproj = (const float*)d_in[4];
  float* out = (float*)d_out;
  char* ws = (char*)d_ws;
  const size_t MB = 1024 * 1024;
  unsigned short* Qb     = (unsigned short*)(ws + 0 * MB);   // [B,N,T,D] bf16, scaled log2e/8
  unsigned short* Kb     = (unsigned short*)(ws + 8 * MB);   // [B,N,T,D]
  unsigned short* Vt     = (unsigned short*)(ws + 24 * MB);  // [B,N,D,T] (written ^T by GEMM)
  unsigned short* attn   = (unsigned short*)(ws + 32 * MB);  // [B,T,C]
  unsigned short* xbf    = (unsigned short*)(ws + 40 * MB);  // [B*T,C]
  unsigned short* Wqkvt  = (unsigned short*)(ws + 48 * MB);  // [3C,C]
  unsigned short* Wprojt = (unsigned short*)(ws + 54 * MB);  // [C,C]

  prep<<<5120, 256, 0, stream>>>(x, xbf, Wqkv, Wqkvt, Wproj, Wprojt);
  gemm_bt<0><<<768, 256, 0, stream>>>(xbf, Wqkvt, bqkv, 4096, 3072, 1024, 24,
                                      Qb, Kb, Vt, nullptr);
  attn_fwd<<<2048, 256, 0, stream>>>(Qb, Kb, Vt, attn);
  gemm_bt<1><<<256, 256, 0, stream>>>(attn, Wprojt, bproj, 4096, 1024, 1024, 8,
                                      nullptr, nullptr, nullptr, out);
}

// Round 11
// 217.045 us; speedup vs baseline: 1.2932x; 1.1295x over previous
//
#include <hip/hip_runtime.h>
#include <hip/hip_bf16.h>
#include <stdint.h>

typedef __attribute__((ext_vector_type(8))) short short8;
typedef __attribute__((ext_vector_type(4))) short s16x4;
typedef __attribute__((ext_vector_type(4))) float floatx4;
typedef __attribute__((ext_vector_type(4))) unsigned short ushortx4;

#define T_LEN 2048
#define C_DIM 1024
#define NH 16
#define HD 64

static __device__ __forceinline__ unsigned short f2bf(float f) {
  union { float f; unsigned u; } v; v.f = f;
  unsigned r = v.u + 0x7fffu + ((v.u >> 16) & 1u);
  return (unsigned short)(r >> 16);
}

static __device__ __forceinline__ void stage16(const void* g, void* l) {
  __builtin_amdgcn_global_load_lds(
      (const __attribute__((address_space(1))) void*)g,
      (__attribute__((address_space(3))) void*)l, 16, 0, 0);
}

// 16x16x16 bf16 MFMA via inline asm (A,B = 2 VGPRs each, C/D = 4; D==C in place)
static __device__ __forceinline__ floatx4 mfma16(s16x4 a, s16x4 b, floatx4 c) {
  asm("v_mfma_f32_16x16x16_bf16 %0, %1, %2, %0" : "+v"(c) : "v"(a), "v"(b));
  return c;
}
// pack 2 f32 -> 1 dword of 2 bf16 (lo = s0, hi = s1)
static __device__ __forceinline__ unsigned cvt_pk_bf16(float lo, float hi) {
  unsigned r;
  asm("v_cvt_pk_bf16_f32 %0, %1, %2" : "=v"(r) : "v"(lo), "v"(hi));
  return r;
}

// ---------- transpose + cast body: in [R][C] f32 -> out [C][R] bf16 ----------
static __device__ __forceinline__ void tc_body(
    const float* __restrict__ in, unsigned short* __restrict__ out,
    int R, int C, int bx, int by, int tid, unsigned short (*tile)[72]) {
  const int r0 = by * 64;
  const int c0 = bx * 64;
#pragma unroll
  for (int e = 0; e < 4; ++e) {
    const int ch = e * 256 + tid;           // 1024 chunks of 4 floats
    const int r = ch >> 4, c4 = (ch & 15) * 4;
    const float4 v = *(const float4*)(in + (long)(r0 + r) * C + c0 + c4);
    tile[r][c4 + 0] = f2bf(v.x);
    tile[r][c4 + 1] = f2bf(v.y);
    tile[r][c4 + 2] = f2bf(v.z);
    tile[r][c4 + 3] = f2bf(v.w);
  }
  __syncthreads();
#pragma unroll
  for (int e = 0; e < 2; ++e) {
    const int ch = e * 256 + tid;           // 512 chunks of 8
    const int c = ch >> 3, k8 = (ch & 7) * 8;
    short8 w;
#pragma unroll
    for (int j = 0; j < 8; ++j) w[j] = (short)tile[k8 + j][c];
    *(short8*)(out + (long)(c0 + c) * R + r0 + k8) = w;
  }
}

// ---- fused prep: cast x (blocks 0..4095), W_qkv^T (4096..4863), W_proj^T (4864..5119) ----
__global__ __launch_bounds__(256) void prep(
    const float* __restrict__ x, unsigned short* __restrict__ xbf,
    const float* __restrict__ Wqkv, unsigned short* __restrict__ Wqkvt,
    const float* __restrict__ Wproj, unsigned short* __restrict__ Wprojt) {
  __shared__ unsigned short tile[64][72];
  const int bid = (int)blockIdx.x;
  const int tid = (int)threadIdx.x;
  if (bid < 4096) {
    const long i = ((long)bid * 256 + tid) * 4;
    const float4 v = *(const float4*)(x + i);
    ushortx4 o;
    o[0] = f2bf(v.x); o[1] = f2bf(v.y); o[2] = f2bf(v.z); o[3] = f2bf(v.w);
    *(ushortx4*)(xbf + i) = o;
  } else if (bid < 4096 + 768) {
    const int t = bid - 4096;
    tc_body(Wqkv, Wqkvt, 1024, 3072, t % 48, t / 48, tid, tile);
  } else {
    const int t = bid - 4864;
    tc_body(Wproj, Wprojt, 1024, 1024, t % 16, t / 16, tid, tile);
  }
}

// ---------------- GEMM: C = A[M,K] * Bt[N,K]^T + bias ----------------
// 128x128 tile, BK=32, 256 threads (4 waves, 2x2 of 64x64 subtiles).
// 2-phase pipelined dbuf LDS; 1-D grid with bijective XCD-chunked swizzle (T1).
// MODE 0: scatter to Q/K/V head layouts (Q scaled 0.125*log2e; V written ^T with
//         8B-packed stores), bf16 out.
// MODE 1: fp32 out row-major [M][N].
#define GSTAGE(BUF, K0) do {                                                          \
    _Pragma("unroll") for (int r = 0; r < 2; ++r) {                                   \
      const int ch = r * 256 + tid;                                                   \
      const int trow = ch >> 2, tcol = (ch & 3) * 8;                                  \
      stage16(Abase + (long)trow * K + (K0) + tcol, &As[BUF][(r * 256 + wid * 64) * 8]); \
      stage16(Bbase + (long)trow * K + (K0) + tcol, &Bs[BUF][(r * 256 + wid * 64) * 8]); \
    } } while (0)

template <int MODE>
__global__ __launch_bounds__(256) void gemm_bt(
    const unsigned short* __restrict__ A,
    const unsigned short* __restrict__ Bt,
    const float* __restrict__ bias,
    int M, int N, int K, int nbx,
    unsigned short* __restrict__ q_out,
    unsigned short* __restrict__ k_out,
    unsigned short* __restrict__ v_out,
    float* __restrict__ f_out) {
  __shared__ unsigned short As[2][128 * 32];
  __shared__ unsigned short Bs[2][128 * 32];
  const int tid = threadIdx.x;
  const int lane = tid & 63;
  const int wid = tid >> 6;
  const int wr = wid >> 1, wc = wid & 1;
  const int lrow = lane & 15, lgrp = lane >> 4;
  // XCD-chunked bijective swizzle (gridDim.x % 8 == 0)
  const int bid = (int)blockIdx.x;
  const int v = (bid & 7) * ((int)gridDim.x >> 3) + (bid >> 3);
  const long row0 = (long)(v / nbx) * 128;
  const long col0 = (long)(v % nbx) * 128;

  floatx4 acc[4][4];
#pragma unroll
  for (int m = 0; m < 4; ++m)
#pragma unroll
    for (int n = 0; n < 4; ++n)
      acc[m][n] = (floatx4){0.f, 0.f, 0.f, 0.f};

  const unsigned short* Abase = A + row0 * K;
  const unsigned short* Bbase = Bt + col0 * K;
  const int NT = K >> 5;

  GSTAGE(0, 0);
  asm volatile("s_waitcnt vmcnt(0)" ::: "memory");
  __builtin_amdgcn_s_barrier();

  int cur = 0;
  for (int t = 0; t < NT - 1; ++t) {
    GSTAGE(cur ^ 1, (t + 1) * 32);          // issue next tile's loads FIRST
    short8 af[4], bf[4];
#pragma unroll
    for (int m = 0; m < 4; ++m)
      af[m] = *(const short8*)&As[cur][(wr * 64 + m * 16 + lrow) * 32 + lgrp * 8];
#pragma unroll
    for (int n = 0; n < 4; ++n)
      bf[n] = *(const short8*)&Bs[cur][(wc * 64 + n * 16 + lrow) * 32 + lgrp * 8];
    __builtin_amdgcn_s_setprio(1);
#pragma unroll
    for (int m = 0; m < 4; ++m)
#pragma unroll
      for (int n = 0; n < 4; ++n)
        acc[m][n] = __builtin_amdgcn_mfma_f32_16x16x32_bf16(af[m], bf[n], acc[m][n], 0, 0, 0);
    __builtin_amdgcn_s_setprio(0);
    asm volatile("s_waitcnt vmcnt(0)" ::: "memory");
    __builtin_amdgcn_s_barrier();
    cur ^= 1;
  }
  {                                          // last tile: no prefetch
    short8 af[4], bf[4];
#pragma unroll
    for (int m = 0; m < 4; ++m)
      af[m] = *(const short8*)&As[cur][(wr * 64 + m * 16 + lrow) * 32 + lgrp * 8];
#pragma unroll
    for (int n = 0; n < 4; ++n)
      bf[n] = *(const short8*)&Bs[cur][(wc * 64 + n * 16 + lrow) * 32 + lgrp * 8];
#pragma unroll
    for (int m = 0; m < 4; ++m)
#pragma unroll
      for (int n = 0; n < 4; ++n)
        acc[m][n] = __builtin_amdgcn_mfma_f32_16x16x32_bf16(af[m], bf[n], acc[m][n], 0, 0, 0);
  }

  if (MODE == 0) {
#pragma unroll
    for (int n = 0; n < 4; ++n) {
      const int c = (int)col0 + wc * 64 + n * 16 + lrow;
      const float bs = bias[c];
      const int sect = c >> 10;            // 0=Q 1=K 2=V
      const int h = (c & 1023) >> 6;
      const int d = c & 63;
      // fold 1/sqrt(64) AND log2(e) into Q (attn uses exp2)
      const float scl = sect == 0 ? 0.18033688011112042f : 1.0f;
#pragma unroll
      for (int m = 0; m < 4; ++m) {
        if (sect == 2) {                   // V^T [bh][D][T]: 4 consecutive t -> 8B store
          const long r0m = row0 + wr * 64 + m * 16 + lgrp * 4;
          const long b = r0m >> 11;
          const long t0 = r0m & 2047;
          ushortx4 pk;
#pragma unroll
          for (int i = 0; i < 4; ++i) pk[i] = f2bf(acc[m][n][i] + bs);
          *(ushortx4*)&v_out[((b * NH + h) * HD + d) * T_LEN + t0] = pk;
        } else {
          unsigned short* dst = sect == 0 ? q_out : k_out;
#pragma unroll
          for (int i = 0; i < 4; ++i) {
            const long r = row0 + wr * 64 + m * 16 + lgrp * 4 + i;
            const long b = r >> 11;
            const long t = r & 2047;
            dst[((b * NH + h) * T_LEN + t) * HD + d] = f2bf((acc[m][n][i] + bs) * scl);
          }
        }
      }
    }
  } else {
#pragma unroll
    for (int n = 0; n < 4; ++n) {
      const int c = (int)col0 + wc * 64 + n * 16 + lrow;
      const float bs = bias[c];
#pragma unroll
      for (int m = 0; m < 4; ++m) {
#pragma unroll
        for (int i = 0; i < 4; ++i) {
          const long r = row0 + wr * 64 + m * 16 + lgrp * 4 + i;
          f_out[r * (long)N + c] = acc[m][n][i] + bs;
        }
      }
    }
  }
}

// ------- flash attention v9: block-cooperative LDS-staged KV, dbuf prefetch -------
// Block = (bh, qblk of 128 q-rows); 4 waves each OWN 32 rows end-to-end (no combine).
// All waves iterate the same KV steps; K[64][64] / V^T[64][64] bf16 tiles staged once
// per block per step via async global_load_lds, double-buffered: stage(next) issued
// before compute(cur), one vmcnt(0)+barrier per step (T3-minimum).
// Swizzle per rule #21: LDS dest linear, global SOURCE pre-XOR'd (16B chunk ^= row&7),
// reads apply the same XOR -> 2-way bank aliasing only (free).
// Swapped QK^T -> lane-local softmax (exp2, exact defer-max); reg-direct PV (16x16x16).
// Grid 512 blocks: XCD-clustered (4 heads/XCD), qblk reversed (long first).
__global__ __launch_bounds__(256) void attn_fwd(
    const unsigned short* __restrict__ Qb,
    const unsigned short* __restrict__ Kb,
    const unsigned short* __restrict__ Vt,
    unsigned short* __restrict__ attn) {
  __shared__ unsigned short Ks[2][4096];   // [s 64][d 64] bf16, chunk-swizzled
  __shared__ unsigned short Vs[2][4096];   // [d 64][s 64] bf16, chunk-swizzled
  const int bid = (int)blockIdx.x;
  const int xcd = bid & 7;
  const int j = bid >> 3;                  // 0..63
  const int bh = xcd * 4 + (j & 3);        // 4 heads per XCD -> KV in XCD L2
  const int qblk = 15 - (j >> 2);          // reversed: long blocks first
  const int b = bh >> 4, h = bh & 15;
  const int tid = (int)threadIdx.x;
  const int wid = tid >> 6;
  const int lane = tid & 63;
  const int lrow = lane & 15, lgrp = lane >> 4;
  const int q0 = qblk * 128 + wid * 32;    // this wave's first q row
  const int myext = q0 + 32;               // exclusive causal extent for this wave
  const int blksteps = (qblk * 128 + 128) >> 6;   // qblk*2 + 2

  const unsigned short* Qh = Qb + (long)bh * T_LEN * HD;
  const unsigned short* Kh = Kb + (long)bh * T_LEN * HD;
  const unsigned short* Vh = Vt + (long)bh * HD * T_LEN;

  // per-thread staging source offsets (16B chunks, XOR-pre-swizzled)
  int koff[2], voff[2];
#pragma unroll
  for (int jj = 0; jj < 2; ++jj) {
    const int c = wid * 128 + jj * 64 + lane;      // chunk id in [0,512)
    const int row = c >> 3;                        // s-row (K) / d-row (V)
    const int cs = ((c & 7) ^ (row & 7)) * 8;      // swizzled chunk -> ushort offset
    koff[jj] = row * HD + cs;
    voff[jj] = row * T_LEN + cs;
  }

#define ASTAGE(BUF, S0) do {                                                         \
    _Pragma("unroll") for (int jj = 0; jj < 2; ++jj)                                 \
      stage16(Kh + (long)(S0) * HD + koff[jj], &Ks[BUF][(wid * 128 + jj * 64) * 8]); \
    _Pragma("unroll") for (int jj = 0; jj < 2; ++jj)                                 \
      stage16(Vh + (long)(S0) + voff[jj], &Vs[BUF][(wid * 128 + jj * 64) * 8]);      \
  } while (0)

  // Q fragments (B operand of swapped QK^T): [qsub][kk]
  short8 aq[2][2];
#pragma unroll
  for (int qs = 0; qs < 2; ++qs)
#pragma unroll
    for (int kk = 0; kk < 2; ++kk)
      aq[qs][kk] = *(const short8*)(Qh + (long)(q0 + qs * 16 + lrow) * HD + kk * 32 + lgrp * 8);

  float m_i[2] = {-1e30f, -1e30f};
  float s_i[2] = {0.f, 0.f};
  floatx4 o[2][4];                         // O[q=16qs+4lg+i][d=16d0+lrow]
#pragma unroll
  for (int qs = 0; qs < 2; ++qs)
#pragma unroll
    for (int d0 = 0; d0 < 4; ++d0) o[qs][d0] = (floatx4){0.f, 0.f, 0.f, 0.f};

  ASTAGE(0, 0);
  asm volatile("s_waitcnt vmcnt(0)" ::: "memory");
  __builtin_amdgcn_s_barrier();

  int cur = 0;
  for (int st = 0; st < blksteps; ++st) {
    const int s0 = st * 64;
    if (st + 1 < blksteps) ASTAGE(cur ^ 1, s0 + 64);   // async prefetch next tile
    if (s0 < myext) {                      // wave-uniform causal skip
      // ---- QK^T from LDS (swizzled b128 reads, ~2-way only) ----
      floatx4 sf[2][4];
#pragma unroll
      for (int qs = 0; qs < 2; ++qs)
#pragma unroll
        for (int sc = 0; sc < 4; ++sc) sf[qs][sc] = (floatx4){0.f, 0.f, 0.f, 0.f};
      __builtin_amdgcn_s_setprio(1);
#pragma unroll
      for (int sc = 0; sc < 4; ++sc) {
        const int row = sc * 16 + lrow;
        const int rsw = row & 7;
        const short8 k0 = *(const short8*)&Ks[cur][row * 64 + (lgrp ^ rsw) * 8];
        const short8 k1 = *(const short8*)&Ks[cur][row * 64 + ((4 + lgrp) ^ rsw) * 8];
        sf[0][sc] = __builtin_amdgcn_mfma_f32_16x16x32_bf16(k0, aq[0][0], sf[0][sc], 0, 0, 0);
        sf[1][sc] = __builtin_amdgcn_mfma_f32_16x16x32_bf16(k0, aq[1][0], sf[1][sc], 0, 0, 0);
        sf[0][sc] = __builtin_amdgcn_mfma_f32_16x16x32_bf16(k1, aq[0][1], sf[0][sc], 0, 0, 0);
        sf[1][sc] = __builtin_amdgcn_mfma_f32_16x16x32_bf16(k1, aq[1][1], sf[1][sc], 0, 0, 0);
      }
      __builtin_amdgcn_s_setprio(0);
      // ---- causal mask (diagonal step only) ----
      if (s0 + 64 > q0) {
#pragma unroll
        for (int qs = 0; qs < 2; ++qs) {
          const int q = q0 + qs * 16 + lrow;
#pragma unroll
          for (int sc = 0; sc < 4; ++sc) {
#pragma unroll
            for (int i = 0; i < 4; ++i) {
              const int s = s0 + sc * 16 + lgrp * 4 + i;
              if (s > q) sf[qs][sc][i] = -1e30f;
            }
          }
        }
      }
      // ---- online softmax: row lane-local + 2 shfl_xor; exp2; exact defer-max ----
      s16x4 pa[2][4];
#pragma unroll
      for (int qs = 0; qs < 2; ++qs) {
        float m0 = fmaxf(fmaxf(sf[qs][0][0], sf[qs][0][1]), fmaxf(sf[qs][0][2], sf[qs][0][3]));
        float m1 = fmaxf(fmaxf(sf[qs][1][0], sf[qs][1][1]), fmaxf(sf[qs][1][2], sf[qs][1][3]));
        float m2 = fmaxf(fmaxf(sf[qs][2][0], sf[qs][2][1]), fmaxf(sf[qs][2][2], sf[qs][2][3]));
        float m3 = fmaxf(fmaxf(sf[qs][3][0], sf[qs][3][1]), fmaxf(sf[qs][3][2], sf[qs][3][3]));
        float mm = fmaxf(fmaxf(m0, m1), fmaxf(m2, m3));
        mm = fmaxf(mm, __shfl_xor(mm, 16));
        mm = fmaxf(mm, __shfl_xor(mm, 32));
        const int grow = !__all(mm <= m_i[qs]);
        float scale = 1.0f;
        if (grow) {
          const float mnew = fmaxf(m_i[qs], mm);
          scale = exp2f(m_i[qs] - mnew);
          m_i[qs] = mnew;
        }
        float rs = 0.f;
#pragma unroll
        for (int sc = 0; sc < 4; ++sc) {
#pragma unroll
          for (int i = 0; i < 4; ++i) {
            const float pv = exp2f(sf[qs][sc][i] - m_i[qs]);
            sf[qs][sc][i] = pv;
            rs += pv;
          }
        }
        rs += __shfl_xor(rs, 16);
        rs += __shfl_xor(rs, 32);
        s_i[qs] = s_i[qs] * scale + rs;
        if (grow) {
#pragma unroll
          for (int i = 0; i < 4; ++i) {
            const float sbc = __shfl(scale, 4 * lgrp + i);
#pragma unroll
            for (int d0 = 0; d0 < 4; ++d0) o[qs][d0][i] *= sbc;
          }
        }
#pragma unroll
        for (int sc = 0; sc < 4; ++sc) {
          union { unsigned u[2]; s16x4 v; } tmp;
          tmp.u[0] = cvt_pk_bf16(sf[qs][sc][0], sf[qs][sc][1]);
          tmp.u[1] = cvt_pk_bf16(sf[qs][sc][2], sf[qs][sc][3]);
          pa[qs][sc] = tmp.v;
        }
      }
      // ---- PV: O += P x V^T from LDS (swizzled b64 reads) ----
      __builtin_amdgcn_s_setprio(1);
#pragma unroll
      for (int d0 = 0; d0 < 4; ++d0) {
        const int d = d0 * 16 + lrow;
        const int dsw = d & 7;
#pragma unroll
        for (int sc = 0; sc < 4; ++sc) {
          const int g = sc * 2 + (lgrp >> 1);
          const s16x4 vb = *(const s16x4*)&Vs[cur][d * 64 + ((g ^ dsw)) * 8 + (lgrp & 1) * 4];
          o[0][d0] = mfma16(pa[0][sc], vb, o[0][d0]);
          o[1][d0] = mfma16(pa[1][sc], vb, o[1][d0]);
        }
      }
      __builtin_amdgcn_s_setprio(0);
    }
    asm volatile("s_waitcnt vmcnt(0)" ::: "memory");
    __builtin_amdgcn_s_barrier();
    cur ^= 1;
  }
#undef ASTAGE

  // ---- epilogue: each wave writes its own rows (no combine) ----
#pragma unroll
  for (int qs = 0; qs < 2; ++qs) {
    float inv[4];
#pragma unroll
    for (int i = 0; i < 4; ++i) inv[i] = 1.0f / __shfl(s_i[qs], 4 * lgrp + i);
#pragma unroll
    for (int d0 = 0; d0 < 4; ++d0) {
#pragma unroll
      for (int i = 0; i < 4; ++i) {
        const int q = q0 + qs * 16 + lgrp * 4 + i;
        attn[(long)(b * T_LEN + q) * C_DIM + h * HD + d0 * 16 + lrow] =
            f2bf(o[qs][d0][i] * inv[i]);
      }
    }
  }
}

extern "C" void kernel_launch(void* const* d_in, const int* in_sizes, int n_in,
                              void* d_out, int out_size, void* d_ws, size_t ws_size,
                              hipStream_t stream) {
  const float* x     = (const float*)d_in[0];
  const float* Wqkv  = (const float*)d_in[1];
  const float* bqkv  = (const float*)d_in[2];
  const float* Wproj = (const float*)d_in[3];
  const float* bproj = (const float*)d_in[4];
  float* out = (float*)d_out;
  char* ws = (char*)d_ws;
  const size_t MB = 1024 * 1024;
  unsigned short* Qb     = (unsigned short*)(ws + 0 * MB);   // [B,N,T,D] bf16, scaled log2e/8
  unsigned short* Kb     = (unsigned short*)(ws + 8 * MB);   // [B,N,T,D]
  unsigned short* Vt     = (unsigned short*)(ws + 24 * MB);  // [B,N,D,T] (written ^T by GEMM)
  unsigned short* attn   = (unsigned short*)(ws + 32 * MB);  // [B,T,C]
  unsigned short* xbf    = (unsigned short*)(ws + 40 * MB);  // [B*T,C]
  unsigned short* Wqkvt  = (unsigned short*)(ws + 48 * MB);  // [3C,C]
  unsigned short* Wprojt = (unsigned short*)(ws + 54 * MB);  // [C,C]

  prep<<<5120, 256, 0, stream>>>(x, xbf, Wqkv, Wqkvt, Wproj, Wprojt);
  gemm_bt<0><<<768, 256, 0, stream>>>(xbf, Wqkvt, bqkv, 4096, 3072, 1024, 24,
                                      Qb, Kb, Vt, nullptr);
  attn_fwd<<<512, 256, 0, stream>>>(Qb, Kb, Vt, attn);
  gemm_bt<1><<<256, 256, 0, stream>>>(attn, Wprojt, bproj, 4096, 1024, 1024, 8,
                                      nullptr, nullptr, nullptr, out);
}

// Round 12
// 197.402 us; speedup vs baseline: 1.4219x; 1.0995x over previous
//
#include <hip/hip_runtime.h>
#include <hip/hip_bf16.h>
#include <stdint.h>

typedef __attribute__((ext_vector_type(8))) short short8;
typedef __attribute__((ext_vector_type(4))) short s16x4;
typedef __attribute__((ext_vector_type(4))) float floatx4;
typedef __attribute__((ext_vector_type(4))) unsigned short ushortx4;

#define T_LEN 2048
#define C_DIM 1024
#define NH 16
#define HD 64

static __device__ __forceinline__ unsigned short f2bf(float f) {
  union { float f; unsigned u; } v; v.f = f;
  unsigned r = v.u + 0x7fffu + ((v.u >> 16) & 1u);
  return (unsigned short)(r >> 16);
}

static __device__ __forceinline__ void stage16(const void* g, void* l) {
  __builtin_amdgcn_global_load_lds(
      (const __attribute__((address_space(1))) void*)g,
      (__attribute__((address_space(3))) void*)l, 16, 0, 0);
}

// 16x16x16 bf16 MFMA via inline asm (A,B = 2 VGPRs each, C/D = 4; D==C in place)
static __device__ __forceinline__ floatx4 mfma16(s16x4 a, s16x4 b, floatx4 c) {
  asm("v_mfma_f32_16x16x16_bf16 %0, %1, %2, %0" : "+v"(c) : "v"(a), "v"(b));
  return c;
}
// pack 2 f32 -> 1 dword of 2 bf16 (lo = s0, hi = s1)
static __device__ __forceinline__ unsigned cvt_pk_bf16(float lo, float hi) {
  unsigned r;
  asm("v_cvt_pk_bf16_f32 %0, %1, %2" : "=v"(r) : "v"(lo), "v"(hi));
  return r;
}

// ---------- transpose + cast body: in [R][C] f32 -> out [C][R] bf16 ----------
static __device__ __forceinline__ void tc_body(
    const float* __restrict__ in, unsigned short* __restrict__ out,
    int R, int C, int bx, int by, int tid, unsigned short (*tile)[72]) {
  const int r0 = by * 64;
  const int c0 = bx * 64;
#pragma unroll
  for (int e = 0; e < 4; ++e) {
    const int ch = e * 256 + tid;           // 1024 chunks of 4 floats
    const int r = ch >> 4, c4 = (ch & 15) * 4;
    const float4 v = *(const float4*)(in + (long)(r0 + r) * C + c0 + c4);
    tile[r][c4 + 0] = f2bf(v.x);
    tile[r][c4 + 1] = f2bf(v.y);
    tile[r][c4 + 2] = f2bf(v.z);
    tile[r][c4 + 3] = f2bf(v.w);
  }
  __syncthreads();
#pragma unroll
  for (int e = 0; e < 2; ++e) {
    const int ch = e * 256 + tid;           // 512 chunks of 8
    const int c = ch >> 3, k8 = (ch & 7) * 8;
    short8 w;
#pragma unroll
    for (int j = 0; j < 8; ++j) w[j] = (short)tile[k8 + j][c];
    *(short8*)(out + (long)(c0 + c) * R + r0 + k8) = w;
  }
}

// ---- fused prep: cast x (blocks 0..4095), W_qkv^T (4096..4863), W_proj^T (4864..5119) ----
__global__ __launch_bounds__(256) void prep(
    const float* __restrict__ x, unsigned short* __restrict__ xbf,
    const float* __restrict__ Wqkv, unsigned short* __restrict__ Wqkvt,
    const float* __restrict__ Wproj, unsigned short* __restrict__ Wprojt) {
  __shared__ unsigned short tile[64][72];
  const int bid = (int)blockIdx.x;
  const int tid = (int)threadIdx.x;
  if (bid < 4096) {
    const long i = ((long)bid * 256 + tid) * 4;
    const float4 v = *(const float4*)(x + i);
    ushortx4 o;
    o[0] = f2bf(v.x); o[1] = f2bf(v.y); o[2] = f2bf(v.z); o[3] = f2bf(v.w);
    *(ushortx4*)(xbf + i) = o;
  } else if (bid < 4096 + 768) {
    const int t = bid - 4096;
    tc_body(Wqkv, Wqkvt, 1024, 3072, t % 48, t / 48, tid, tile);
  } else {
    const int t = bid - 4864;
    tc_body(Wproj, Wprojt, 1024, 1024, t % 16, t / 16, tid, tile);
  }
}

// ---------------- GEMM: C = A[M,K] * Bt[N,K]^T + bias ----------------
// 128x128 tile, BK=32, 256 threads (4 waves, 2x2 of 64x64 subtiles).
// 2-phase pipelined dbuf LDS; 1-D grid with bijective XCD-chunked swizzle (T1).
// MODE 0: scatter to Q/K/V head layouts (Q scaled 0.125*log2e; V written ^T with
//         8B-packed stores), bf16 out.
// MODE 1: fp32 out row-major [M][N].
#define GSTAGE(BUF, K0) do {                                                          \
    _Pragma("unroll") for (int r = 0; r < 2; ++r) {                                   \
      const int ch = r * 256 + tid;                                                   \
      const int trow = ch >> 2, tcol = (ch & 3) * 8;                                  \
      stage16(Abase + (long)trow * K + (K0) + tcol, &As[BUF][(r * 256 + wid * 64) * 8]); \
      stage16(Bbase + (long)trow * K + (K0) + tcol, &Bs[BUF][(r * 256 + wid * 64) * 8]); \
    } } while (0)

template <int MODE>
__global__ __launch_bounds__(256) void gemm_bt(
    const unsigned short* __restrict__ A,
    const unsigned short* __restrict__ Bt,
    const float* __restrict__ bias,
    int M, int N, int K, int nbx,
    unsigned short* __restrict__ q_out,
    unsigned short* __restrict__ k_out,
    unsigned short* __restrict__ v_out,
    float* __restrict__ f_out) {
  __shared__ unsigned short As[2][128 * 32];
  __shared__ unsigned short Bs[2][128 * 32];
  const int tid = threadIdx.x;
  const int lane = tid & 63;
  const int wid = tid >> 6;
  const int wr = wid >> 1, wc = wid & 1;
  const int lrow = lane & 15, lgrp = lane >> 4;
  // XCD-chunked bijective swizzle (gridDim.x % 8 == 0)
  const int bid = (int)blockIdx.x;
  const int v = (bid & 7) * ((int)gridDim.x >> 3) + (bid >> 3);
  const long row0 = (long)(v / nbx) * 128;
  const long col0 = (long)(v % nbx) * 128;

  floatx4 acc[4][4];
#pragma unroll
  for (int m = 0; m < 4; ++m)
#pragma unroll
    for (int n = 0; n < 4; ++n)
      acc[m][n] = (floatx4){0.f, 0.f, 0.f, 0.f};

  const unsigned short* Abase = A + row0 * K;
  const unsigned short* Bbase = Bt + col0 * K;
  const int NT = K >> 5;

  GSTAGE(0, 0);
  asm volatile("s_waitcnt vmcnt(0)" ::: "memory");
  __builtin_amdgcn_s_barrier();

  int cur = 0;
  for (int t = 0; t < NT - 1; ++t) {
    GSTAGE(cur ^ 1, (t + 1) * 32);          // issue next tile's loads FIRST
    short8 af[4], bf[4];
#pragma unroll
    for (int m = 0; m < 4; ++m)
      af[m] = *(const short8*)&As[cur][(wr * 64 + m * 16 + lrow) * 32 + lgrp * 8];
#pragma unroll
    for (int n = 0; n < 4; ++n)
      bf[n] = *(const short8*)&Bs[cur][(wc * 64 + n * 16 + lrow) * 32 + lgrp * 8];
    __builtin_amdgcn_s_setprio(1);
#pragma unroll
    for (int m = 0; m < 4; ++m)
#pragma unroll
      for (int n = 0; n < 4; ++n)
        acc[m][n] = __builtin_amdgcn_mfma_f32_16x16x32_bf16(af[m], bf[n], acc[m][n], 0, 0, 0);
    __builtin_amdgcn_s_setprio(0);
    asm volatile("s_waitcnt vmcnt(0)" ::: "memory");
    __builtin_amdgcn_s_barrier();
    cur ^= 1;
  }
  {                                          // last tile: no prefetch
    short8 af[4], bf[4];
#pragma unroll
    for (int m = 0; m < 4; ++m)
      af[m] = *(const short8*)&As[cur][(wr * 64 + m * 16 + lrow) * 32 + lgrp * 8];
#pragma unroll
    for (int n = 0; n < 4; ++n)
      bf[n] = *(const short8*)&Bs[cur][(wc * 64 + n * 16 + lrow) * 32 + lgrp * 8];
#pragma unroll
    for (int m = 0; m < 4; ++m)
#pragma unroll
      for (int n = 0; n < 4; ++n)
        acc[m][n] = __builtin_amdgcn_mfma_f32_16x16x32_bf16(af[m], bf[n], acc[m][n], 0, 0, 0);
  }

  if (MODE == 0) {
#pragma unroll
    for (int n = 0; n < 4; ++n) {
      const int c = (int)col0 + wc * 64 + n * 16 + lrow;
      const float bs = bias[c];
      const int sect = c >> 10;            // 0=Q 1=K 2=V
      const int h = (c & 1023) >> 6;
      const int d = c & 63;
      // fold 1/sqrt(64) AND log2(e) into Q (attn uses exp2)
      const float scl = sect == 0 ? 0.18033688011112042f : 1.0f;
#pragma unroll
      for (int m = 0; m < 4; ++m) {
        if (sect == 2) {                   // V^T [bh][D][T]: 4 consecutive t -> 8B store
          const long r0m = row0 + wr * 64 + m * 16 + lgrp * 4;
          const long b = r0m >> 11;
          const long t0 = r0m & 2047;
          ushortx4 pk;
#pragma unroll
          for (int i = 0; i < 4; ++i) pk[i] = f2bf(acc[m][n][i] + bs);
          *(ushortx4*)&v_out[((b * NH + h) * HD + d) * T_LEN + t0] = pk;
        } else {
          unsigned short* dst = sect == 0 ? q_out : k_out;
#pragma unroll
          for (int i = 0; i < 4; ++i) {
            const long r = row0 + wr * 64 + m * 16 + lgrp * 4 + i;
            const long b = r >> 11;
            const long t = r & 2047;
            dst[((b * NH + h) * T_LEN + t) * HD + d] = f2bf((acc[m][n][i] + bs) * scl);
          }
        }
      }
    }
  } else {
#pragma unroll
    for (int n = 0; n < 4; ++n) {
      const int c = (int)col0 + wc * 64 + n * 16 + lrow;
      const float bs = bias[c];
#pragma unroll
      for (int m = 0; m < 4; ++m) {
#pragma unroll
        for (int i = 0; i < 4; ++i) {
          const long r = row0 + wr * 64 + m * 16 + lgrp * 4 + i;
          f_out[r * (long)N + c] = acc[m][n][i] + bs;
        }
      }
    }
  }
}

// ------- flash attention v10: 16-row waves, 64-row blocks, 1024 blocks -------
// v9 structure (LDS-staged KV, dbuf async prefetch, source-XOR swizzle) with wave
// granularity halved: wave = 16 q-rows, block = 64 rows x 4 waves -> 1024 blocks
// = 4 blocks/CU co-resident (LDS cap 5) = 4 waves/SIMD, 2x the latency hiding.
// Swapped QK^T -> lane-local softmax (exp2, exact defer-max); reg-direct PV.
// Grid XCD-clustered (4 heads/XCD), qblk reversed (long first).
__global__ __launch_bounds__(256) void attn_fwd(
    const unsigned short* __restrict__ Qb,
    const unsigned short* __restrict__ Kb,
    const unsigned short* __restrict__ Vt,
    unsigned short* __restrict__ attn) {
  __shared__ unsigned short Ks[2][4096];   // [s 64][d 64] bf16, chunk-swizzled
  __shared__ unsigned short Vs[2][4096];   // [d 64][s 64] bf16, chunk-swizzled
  const int bid = (int)blockIdx.x;
  const int xcd = bid & 7;
  const int j = bid >> 3;                  // 0..127
  const int bh = xcd * 4 + (j & 3);        // 4 heads per XCD -> KV in XCD L2
  const int qblk = 31 - (j >> 2);          // 0..31, reversed: long blocks first
  const int b = bh >> 4, h = bh & 15;
  const int tid = (int)threadIdx.x;
  const int wid = tid >> 6;
  const int lane = tid & 63;
  const int lrow = lane & 15, lgrp = lane >> 4;
  const int q0 = qblk * 64 + wid * 16;     // this wave's first q row (16 rows)
  const int myext = q0 + 16;               // exclusive causal extent for this wave
  const int blksteps = qblk + 1;           // ceil((qblk*64+64)/64)

  const unsigned short* Qh = Qb + (long)bh * T_LEN * HD;
  const unsigned short* Kh = Kb + (long)bh * T_LEN * HD;
  const unsigned short* Vh = Vt + (long)bh * HD * T_LEN;

  // per-thread staging source offsets (16B chunks, XOR-pre-swizzled)
  int koff[2], voff[2];
#pragma unroll
  for (int jj = 0; jj < 2; ++jj) {
    const int c = wid * 128 + jj * 64 + lane;      // chunk id in [0,512)
    const int row = c >> 3;                        // s-row (K) / d-row (V)
    const int cs = ((c & 7) ^ (row & 7)) * 8;      // swizzled chunk -> ushort offset
    koff[jj] = row * HD + cs;
    voff[jj] = row * T_LEN + cs;
  }

#define ASTAGE(BUF, S0) do {                                                         \
    _Pragma("unroll") for (int jj = 0; jj < 2; ++jj)                                 \
      stage16(Kh + (long)(S0) * HD + koff[jj], &Ks[BUF][(wid * 128 + jj * 64) * 8]); \
    _Pragma("unroll") for (int jj = 0; jj < 2; ++jj)                                 \
      stage16(Vh + (long)(S0) + voff[jj], &Vs[BUF][(wid * 128 + jj * 64) * 8]);      \
  } while (0)

  // Q fragments (B operand of swapped QK^T): [kk]
  short8 aq[2];
#pragma unroll
  for (int kk = 0; kk < 2; ++kk)
    aq[kk] = *(const short8*)(Qh + (long)(q0 + lrow) * HD + kk * 32 + lgrp * 8);

  float m_i = -1e30f;
  float s_i = 0.f;
  floatx4 o[4];                            // O[q=4lg+i][d=16d0+lrow]
#pragma unroll
  for (int d0 = 0; d0 < 4; ++d0) o[d0] = (floatx4){0.f, 0.f, 0.f, 0.f};

  ASTAGE(0, 0);
  asm volatile("s_waitcnt vmcnt(0)" ::: "memory");
  __builtin_amdgcn_s_barrier();

  int cur = 0;
  for (int st = 0; st < blksteps; ++st) {
    const int s0 = st * 64;
    if (st + 1 < blksteps) ASTAGE(cur ^ 1, s0 + 64);   // async prefetch next tile
    if (s0 < myext) {                      // wave-uniform causal skip
      // ---- QK^T from LDS (swizzled b128 reads) ----
      floatx4 sf[4];
#pragma unroll
      for (int sc = 0; sc < 4; ++sc) sf[sc] = (floatx4){0.f, 0.f, 0.f, 0.f};
      __builtin_amdgcn_s_setprio(1);
#pragma unroll
      for (int sc = 0; sc < 4; ++sc) {
        const int row = sc * 16 + lrow;
        const int rsw = row & 7;
        const short8 k0 = *(const short8*)&Ks[cur][row * 64 + (lgrp ^ rsw) * 8];
        const short8 k1 = *(const short8*)&Ks[cur][row * 64 + ((4 + lgrp) ^ rsw) * 8];
        sf[sc] = __builtin_amdgcn_mfma_f32_16x16x32_bf16(k0, aq[0], sf[sc], 0, 0, 0);
        sf[sc] = __builtin_amdgcn_mfma_f32_16x16x32_bf16(k1, aq[1], sf[sc], 0, 0, 0);
      }
      __builtin_amdgcn_s_setprio(0);
      // ---- causal mask (diagonal step only) ----
      if (s0 + 64 > q0) {
        const int q = q0 + lrow;
#pragma unroll
        for (int sc = 0; sc < 4; ++sc) {
#pragma unroll
          for (int i = 0; i < 4; ++i) {
            const int s = s0 + sc * 16 + lgrp * 4 + i;
            if (s > q) sf[sc][i] = -1e30f;
          }
        }
      }
      // ---- online softmax: row lane-local + 2 shfl_xor; exp2; exact defer-max ----
      float m0 = fmaxf(fmaxf(sf[0][0], sf[0][1]), fmaxf(sf[0][2], sf[0][3]));
      float m1 = fmaxf(fmaxf(sf[1][0], sf[1][1]), fmaxf(sf[1][2], sf[1][3]));
      float m2 = fmaxf(fmaxf(sf[2][0], sf[2][1]), fmaxf(sf[2][2], sf[2][3]));
      float m3 = fmaxf(fmaxf(sf[3][0], sf[3][1]), fmaxf(sf[3][2], sf[3][3]));
      float mm = fmaxf(fmaxf(m0, m1), fmaxf(m2, m3));
      mm = fmaxf(mm, __shfl_xor(mm, 16));
      mm = fmaxf(mm, __shfl_xor(mm, 32));
      const int grow = !__all(mm <= m_i);
      float scale = 1.0f;
      if (grow) {
        const float mnew = fmaxf(m_i, mm);
        scale = exp2f(m_i - mnew);
        m_i = mnew;
      }
      float rs = 0.f;
      s16x4 pa[4];
#pragma unroll
      for (int sc = 0; sc < 4; ++sc) {
#pragma unroll
        for (int i = 0; i < 4; ++i) {
          const float pv = exp2f(sf[sc][i] - m_i);
          sf[sc][i] = pv;
          rs += pv;
        }
      }
      rs += __shfl_xor(rs, 16);
      rs += __shfl_xor(rs, 32);
      s_i = s_i * scale + rs;
      if (grow) {
#pragma unroll
        for (int i = 0; i < 4; ++i) {
          const float sbc = __shfl(scale, 4 * lgrp + i);
#pragma unroll
          for (int d0 = 0; d0 < 4; ++d0) o[d0][i] *= sbc;
        }
      }
#pragma unroll
      for (int sc = 0; sc < 4; ++sc) {
        union { unsigned u[2]; s16x4 v; } tmp;
        tmp.u[0] = cvt_pk_bf16(sf[sc][0], sf[sc][1]);
        tmp.u[1] = cvt_pk_bf16(sf[sc][2], sf[sc][3]);
        pa[sc] = tmp.v;
      }
      // ---- PV: O += P x V^T from LDS (swizzled b64 reads) ----
      __builtin_amdgcn_s_setprio(1);
#pragma unroll
      for (int d0 = 0; d0 < 4; ++d0) {
        const int d = d0 * 16 + lrow;
        const int dsw = d & 7;
#pragma unroll
        for (int sc = 0; sc < 4; ++sc) {
          const int g = sc * 2 + (lgrp >> 1);
          const s16x4 vb = *(const s16x4*)&Vs[cur][d * 64 + ((g ^ dsw)) * 8 + (lgrp & 1) * 4];
          o[d0] = mfma16(pa[sc], vb, o[d0]);
        }
      }
      __builtin_amdgcn_s_setprio(0);
    }
    asm volatile("s_waitcnt vmcnt(0)" ::: "memory");
    __builtin_amdgcn_s_barrier();
    cur ^= 1;
  }
#undef ASTAGE

  // ---- epilogue: each wave writes its own 16 rows ----
  float inv[4];
#pragma unroll
  for (int i = 0; i < 4; ++i) inv[i] = 1.0f / __shfl(s_i, 4 * lgrp + i);
#pragma unroll
  for (int d0 = 0; d0 < 4; ++d0) {
#pragma unroll
    for (int i = 0; i < 4; ++i) {
      const int q = q0 + lgrp * 4 + i;
      attn[(long)(b * T_LEN + q) * C_DIM + h * HD + d0 * 16 + lrow] =
          f2bf(o[d0][i] * inv[i]);
    }
  }
}

extern "C" void kernel_launch(void* const* d_in, const int* in_sizes, int n_in,
                              void* d_out, int out_size, void* d_ws, size_t ws_size,
                              hipStream_t stream) {
  const float* x     = (const float*)d_in[0];
  const float* Wqkv  = (const float*)d_in[1];
  const float* bqkv  = (const float*)d_in[2];
  const float* Wproj = (const float*)d_in[3];
  const float* bproj = (const float*)d_in[4];
  float* out = (float*)d_out;
  char* ws = (char*)d_ws;
  const size_t MB = 1024 * 1024;
  unsigned short* Qb     = (unsigned short*)(ws + 0 * MB);   // [B,N,T,D] bf16, scaled log2e/8
  unsigned short* Kb     = (unsigned short*)(ws + 8 * MB);   // [B,N,T,D]
  unsigned short* Vt     = (unsigned short*)(ws + 24 * MB);  // [B,N,D,T] (written ^T by GEMM)
  unsigned short* attn   = (unsigned short*)(ws + 32 * MB);  // [B,T,C]
  unsigned short* xbf    = (unsigned short*)(ws + 40 * MB);  // [B*T,C]
  unsigned short* Wqkvt  = (unsigned short*)(ws + 48 * MB);  // [3C,C]
  unsigned short* Wprojt = (unsigned short*)(ws + 54 * MB);  // [C,C]

  prep<<<5120, 256, 0, stream>>>(x, xbf, Wqkv, Wqkvt, Wproj, Wprojt);
  gemm_bt<0><<<768, 256, 0, stream>>>(xbf, Wqkvt, bqkv, 4096, 3072, 1024, 24,
                                      Qb, Kb, Vt, nullptr);
  attn_fwd<<<1024, 256, 0, stream>>>(Qb, Kb, Vt, attn);
  gemm_bt<1><<<256, 256, 0, stream>>>(attn, Wprojt, bproj, 4096, 1024, 1024, 8,
                                      nullptr, nullptr, nullptr, out);
}